// Round 4
// baseline (294.923 us; speedup 1.0000x reference)
//
#include <hip/hip_runtime.h>
#include <cstdint>
#include <cmath>
#include <cstddef>

typedef unsigned int u32;
typedef unsigned short u16;
typedef __bf16 bf16x8 __attribute__((ext_vector_type(8)));
typedef float f32x4 __attribute__((ext_vector_type(4)));
typedef u32 u32x4 __attribute__((ext_vector_type(4)));
typedef u32 u32x2 __attribute__((ext_vector_type(2)));

#define DEV static __device__ __forceinline__

// ---------- helpers ----------
DEV float bflo(u32 u) { return __uint_as_float(u << 16); }
DEV float bfhi(u32 u) { return __uint_as_float(u & 0xffff0000u); }
DEV u16 f2bf(float f) {               // RNE fp32 -> bf16
  u32 u = __float_as_uint(f);
  u += 0x7fffu + ((u >> 16) & 1u);
  return (u16)(u >> 16);
}
DEV f32x4 unpack_bf4(u32x2 r) {
  return (f32x4){bflo(r[0]), bfhi(r[0]), bflo(r[1]), bfhi(r[1])};
}
DEV float wredsum(float v) {
#pragma unroll
  for (int o = 32; o; o >>= 1) v += __shfl_xor(v, o, 64);
  return v;
}

// async global->LDS, 16B per lane. LDS dest is wave-uniform base + lane*16.
DEV void gload_lds16(const u16* g, u16* lds_base) {
  __builtin_amdgcn_global_load_lds((const __attribute__((address_space(1))) void*)g,
                                   (__attribute__((address_space(3))) void*)lds_base,
                                   16, 0, 0);
}

// ---------- fused casts + workspace pad zeroing ----------
__global__ __launch_bounds__(256) void fused_cast(const float* __restrict__ x,
                                                  const float* __restrict__ aw,
                                                  const float* __restrict__ pw,
                                                  const float* __restrict__ cw,
                                                  u16* __restrict__ xb,
                                                  u16* __restrict__ wab,
                                                  u16* __restrict__ wpb,
                                                  u16* __restrict__ wcb,
                                                  u16* __restrict__ kcb,
                                                  u16* __restrict__ vcb) {
  const int blk = blockIdx.x;
  if (blk < 12288) {
    const float* src;
    u16* dst;
    int base;
    if (blk < 8192) { src = x; dst = xb; base = blk; }
    else if (blk < 11264) { src = aw; dst = wab; base = blk - 8192; }
    else { src = pw; dst = wpb; base = blk - 11264; }
    const size_t idx = ((size_t)base * 256 + threadIdx.x) * 4;
    const f32x4 v = *(const f32x4*)&src[idx];
    u32x2 r;
    r[0] = (u32)f2bf(v[0]) | ((u32)f2bf(v[1]) << 16);
    r[1] = (u32)f2bf(v[2]) | ((u32)f2bf(v[3]) << 16);
    *(u32x2*)&dst[idx] = r;
  } else if (blk < 12800) {
    // conv_w [64][64][32] (o,i,kk) fp32 -> Wc[o][kk*64+i] bf16
    const int idx = (blk - 12288) * 256 + threadIdx.x;
    const int o = idx >> 11;
    const int rest = idx & 2047;
    const int i = rest >> 5;
    const int kk = rest & 31;
    wcb[(o << 11) + (kk << 6) + i] = f2bf(cw[idx]);
  } else {
    for (int i = threadIdx.x; i < 8192; i += 256) {
      const int bh = i >> 6, d = i & 63;
      kcb[bh * 4096 + 63 * 64 + d] = 0;   // K-block row 63 (pad)
      vcb[bh * 4096 + d * 64 + 63] = 0;   // V col 63 (pad)
    }
  }
}

// ---------- MFMA GEMM: out[M,N] = A[M,K](bf16) * B[N,K](bf16)^T ----------
// 128x128 tile, BK=64, 256 threads; global_load_lds width=16.
// XOR-swizzled LDS. At the m97-structure ceiling (~935 TF); 8-phase port
// without the full derived-waits schedule regressed (round 1).
// Round-4: 1-D grid + bijective XCD-chunk swizzle (T1): each XCD gets a
// contiguous wg chunk (bx fast) so its ~3 B-panels stay L2-resident ->
// staged-load latency (the vmcnt(0) barrier-drain term) drops.
template <int OUT_BF16>
__global__ __launch_bounds__(256, 4) void gemm_bt(const u16* __restrict__ A,
                                                  const u16* __restrict__ Bm,
                                                  void* __restrict__ out,
                                                  int M, int N, int K) {
  __shared__ u16 As[128 * 64];
  __shared__ u16 Bs[128 * 64];
  const int tid = threadIdx.x;
  const int lane = tid & 63;
  const int w = tid >> 6;
  const int nchunk = gridDim.x >> 3;                       // nwg divisible by 8
  const int wg = (blockIdx.x & 7) * nchunk + (blockIdx.x >> 3);
  const int row0 = (wg & 63) * 128;                        // M=8192 -> 64 row tiles
  const int col0 = (wg >> 6) * 128;
  const int wm = (w >> 1) * 64, wn = (w & 1) * 64;
  const int lr = lane & 15, lq = lane >> 4;
  const int srow = lane >> 3;
  const int scol = ((lane & 7) ^ (srow & 7)) * 8;
  const int pgA = ((lq ^ (lr & 7)) * 8);  // ks=0; ks=1 is pgA ^ 32

  f32x4 acc[4][4] = {};

  for (int k0 = 0; k0 < K; k0 += 64) {
    __syncthreads();
#pragma unroll
    for (int c = 0; c < 4; ++c) {
      const int base_r = w * 32 + c * 8;   // wave-uniform
      gload_lds16(&A[(size_t)(row0 + base_r + srow) * K + k0 + scol], &As[base_r * 64]);
      gload_lds16(&Bm[(size_t)(col0 + base_r + srow) * K + k0 + scol], &Bs[base_r * 64]);
    }
    __syncthreads();
#pragma unroll
    for (int ks = 0; ks < 2; ++ks) {
      const int pg = pgA ^ (ks << 5);
      bf16x8 af[4], bfr[4];
#pragma unroll
      for (int i = 0; i < 4; ++i) {
        af[i] = *(const bf16x8*)&As[(wm + i * 16 + lr) * 64 + pg];
        bfr[i] = *(const bf16x8*)&Bs[(wn + i * 16 + lr) * 64 + pg];
      }
#pragma unroll
      for (int i = 0; i < 4; ++i)
#pragma unroll
        for (int j = 0; j < 4; ++j)
          acc[i][j] = __builtin_amdgcn_mfma_f32_16x16x32_bf16(af[i], bfr[j], acc[i][j], 0, 0, 0);
    }
  }
#pragma unroll
  for (int i = 0; i < 4; ++i)
#pragma unroll
    for (int j = 0; j < 4; ++j)
#pragma unroll
      for (int rr = 0; rr < 4; ++rr) {
        const int gr = row0 + wm + i * 16 + lq * 4 + rr;
        const int gc = col0 + wn + j * 16 + lr;
        const float v = acc[i][j][rr];
        if (OUT_BF16)
          ((u16*)out)[(size_t)gr * N + gc] = f2bf(v);
        else
          ((float*)out)[(size_t)gr * N + gc] = v;
      }
}

// ---------- compression: conv(K=32,stride16) as GEMM + LN(64) + GELU ----------
// BM=32 tiles, grid (252, 2); BK=128 double-buffered (round-2 win).
__global__ __launch_bounds__(256) void compress_kernel(const u16* __restrict__ qkv,
                                                       const u16* __restrict__ Wc,
                                                       const float* __restrict__ ln_w,
                                                       u16* __restrict__ kcb,
                                                       u16* __restrict__ vcb) {
  __shared__ u16 As[2][32 * 128];   // 16 KB
  __shared__ u16 Bs[2][64 * 128];   // 32 KB
  __shared__ float Cs[32][65];      // 8.3 KB
  const int tid = threadIdx.x;
  const int lane = tid & 63, w = tid >> 6;
  const int lr = lane & 15, lq = lane >> 4;
  const int r0 = blockIdx.x * 32;
  const int srcoff = 1024 + (int)blockIdx.y * 1024;

  size_t abase[2];
#pragma unroll
  for (int g2 = 0; g2 < 2; ++g2) {
    const int r = 8 * w + 4 * g2 + (lane >> 4);       // 0..31
    const int gr = r0 + r;
    const int bh = gr / 63;
    const int nb = gr - bh * 63;
    const int b = bh >> 4, h = bh & 15;
    const int jbit = (lane >> 3) & 1;                 // L>>3
    const int icol = ((lane & 7) ^ (r & 7)) * 8;      // (L&7)*8
    abase[g2] = (size_t)(b * 1024 + nb * 16 + jbit) * 3072 + srcoff + h * 64 + icol;
  }
  size_t bbase[4];
#pragma unroll
  for (int c = 0; c < 4; ++c) {
    const int rB = 16 * w + 4 * c + (lane >> 4);      // 0..63
    const int Lcol = (((lane & 7) ^ (rB & 7)) | (lane & 8)) * 8;
    bbase[c] = (size_t)rB * 2048 + Lcol;
  }

  auto stage = [&](int it, int bs) {
#pragma unroll
    for (int g2 = 0; g2 < 2; ++g2)
      gload_lds16(&qkv[abase[g2] + (size_t)it * 6144], &As[bs][(8 * w + 4 * g2) * 128]);
#pragma unroll
    for (int c = 0; c < 4; ++c)
      gload_lds16(&Wc[bbase[c] + (size_t)it * 128], &Bs[bs][(16 * w + 4 * c) * 128]);
  };

  const int rw = (w & 1) * 16;   // row-half this wave computes
  const int cw = (w >> 1) * 32;  // col-half this wave computes
  f32x4 acc[2] = {};

  stage(0, 0);
  for (int it = 0; it < 16; ++it) {
    const int cur = it & 1;
    __syncthreads();               // drains stage for buf cur
    if (it < 15) stage(it + 1, cur ^ 1);
    const int rowA = rw + lr;
#pragma unroll
    for (int ks = 0; ks < 4; ++ks) {
      const int L = ks * 4 + lq;                       // logical 8-hw group 0..15
      const int pgA = (((L & 7) ^ (rowA & 7)) | (L & 8)) * 8;
      const bf16x8 af = *(const bf16x8*)&As[cur][rowA * 128 + pgA];
#pragma unroll
      for (int j = 0; j < 2; ++j) {
        const int rowB = cw + j * 16 + lr;
        const int pgB = (((L & 7) ^ (rowB & 7)) | (L & 8)) * 8;
        const bf16x8 bfr = *(const bf16x8*)&Bs[cur][rowB * 128 + pgB];
        acc[j] = __builtin_amdgcn_mfma_f32_16x16x32_bf16(af, bfr, acc[j], 0, 0, 0);
      }
    }
  }
  __syncthreads();
#pragma unroll
  for (int j = 0; j < 2; ++j)
#pragma unroll
    for (int rr = 0; rr < 4; ++rr)
      Cs[rw + lq * 4 + rr][cw + j * 16 + lr] = acc[j][rr];
  __syncthreads();
  if (tid < 32) {
    const int gr2 = r0 + tid;
    const int bh2 = gr2 / 63;
    const int nb2 = gr2 - bh2 * 63;
    float s = 0.f, s2 = 0.f;
#pragma unroll 8
    for (int d = 0; d < 64; ++d) {
      const float xv = Cs[tid][d];
      s += xv;
      s2 += xv * xv;
    }
    const float m = s * (1.f / 64.f);
    const float inv = rsqrtf(s2 * (1.f / 64.f) - m * m + 1e-5f);
    if (blockIdx.y == 0) {
      const size_t gb = (size_t)bh2 * 4096 + nb2 * 64;
#pragma unroll 8
      for (int d = 0; d < 64; ++d) {
        const float z = (Cs[tid][d] - m) * inv * ln_w[d];
        kcb[gb + d] = f2bf(0.5f * z * (1.f + erff(z * 0.70710678118f)));
      }
    } else {
      const size_t gb = (size_t)bh2 * 4096 + nb2;
#pragma unroll 8
      for (int d = 0; d < 64; ++d) {
        const float z = (Cs[tid][d] - m) * inv * ln_w[d];
        vcb[gb + d * 64] = f2bf(0.5f * z * (1.f + erff(z * 0.70710678118f)));
      }
    }
  }
}

// ---------- fused attention: local banded (window 129) + compressed-KV ----------
// grid (B*H, T/64); block 256 = 4 waves; wave w owns query rows w*16..w*16+15.
// Round-3: swizzled Vt (bank-conflict fix), [32][200] d-half ping-pong
// (LDS 40448 -> 4 blocks/CU), reg-prefetched Kc/Vc (T14).
__global__ __launch_bounds__(256, 4) void attn_fused(const u16* __restrict__ qkv,
                                                     const u16* __restrict__ kcb,
                                                     const u16* __restrict__ vcb,
                                                     u16* __restrict__ loc,
                                                     u16* __restrict__ outc) {
  __shared__ __align__(16) char smem[40448];
  u16* Ks = (u16*)smem;            // [192][72] bf16, local QK phase (27648 B)
  u16* Ps = (u16*)smem;            // [64][200] bf16, overlays Ks after QK (25600 B)
  u16* Vt = (u16*)(smem + 27648);  // [32][200] bf16, swizzled d-half ping-pong
  u16* Kc = (u16*)smem;            // [64][72] compressed phase
  u16* Vc = (u16*)(smem + 9216);   // [64][72]
  u16* Pc = (u16*)(smem + 18432);  // [64][72]
  const int bh = blockIdx.x;
  const int b = bh >> 4, h = bh & 15;
  const int i0 = blockIdx.y * 64;
  const int jbase = i0 - 128;
  const int tid = threadIdx.x;
  const int lane = tid & 63, w = tid >> 6;
  const int lr = lane & 15, lq = lane >> 4;
  const int j3 = lane & 3;            // (Vt local row)>>3 for this lane's dims
  const int dh1 = (lane >> 2) & 1;    // 1 if this lane's V dims are >= 32

  // stage K into LDS, V into regs; Q fragments from global
  u32x4 vreg[6];
#pragma unroll
  for (int c = 0; c < 6; ++c) {
    const int lin = c * 256 + tid;
    const int s = lin >> 3, d0 = (lin & 7) * 8;
    const int j = jbase + s;
    u32x4 kval = {0, 0, 0, 0}, vval = {0, 0, 0, 0};
    if (j >= 0) {
      const size_t ro = (size_t)(b * 1024 + j) * 3072 + h * 64 + d0;
      kval = *(const u32x4*)&qkv[ro + 1024];
      vval = *(const u32x4*)&qkv[ro + 2048];
    }
    vreg[c] = vval;
    *(u32x4*)&Ks[s * 72 + d0] = kval;
  }
  // write Vt half0 (d<32) now: region disjoint from Ks, barrier (1) covers it
  if (!dh1) {
    const int d0 = (lane & 7) * 8;    // 0..24
#pragma unroll
    for (int c = 0; c < 6; ++c) {
      const int s = (c * 256 + tid) >> 3;
      const int sc = (((s >> 3) ^ j3) << 3) + (s & 7);
      const u32x4 val = vreg[c];
#pragma unroll
      for (int q = 0; q < 4; ++q) {
        Vt[(d0 + 2 * q) * 200 + sc] = (u16)(val[q] & 0xffffu);
        Vt[(d0 + 2 * q + 1) * 200 + sc] = (u16)(val[q] >> 16);
      }
    }
  }
  bf16x8 qf[2];
  {
    const size_t qrow = (size_t)(b * 1024 + i0 + w * 16 + lr) * 3072 + h * 64;
#pragma unroll
    for (int ks = 0; ks < 2; ++ks) qf[ks] = *(const bf16x8*)&qkv[qrow + ks * 32 + lq * 8];
  }
  // T14: prefetch compressed K/V (L2-resident) for phase 2
  const size_t cb = (size_t)bh * 4096;
  u32x4 kcreg[2], vcreg[2];
#pragma unroll
  for (int c2 = 0; c2 < 2; ++c2) {
    const int i2 = c2 * 256 + tid;
    const size_t o2 = (size_t)(i2 >> 3) * 64 + (i2 & 7) * 8;
    kcreg[c2] = *(const u32x4*)&kcb[cb + o2];
    vcreg[c2] = *(const u32x4*)&vcb[cb + o2];
  }
  __syncthreads();  // (1) Ks + Vt-half0 visible

  // S = Q*K^T over the 9 band tiles jt = w..w+8
  f32x4 sa[9];
#pragma unroll
  for (int j9 = 0; j9 < 9; ++j9) sa[j9] = (f32x4){0.f, 0.f, 0.f, 0.f};
#pragma unroll
  for (int ks = 0; ks < 2; ++ks)
#pragma unroll
    for (int j9 = 0; j9 < 9; ++j9) {
      const int jt = w + j9;
      const bf16x8 kf = *(const bf16x8*)&Ks[(jt * 16 + lr) * 72 + ks * 32 + lq * 8];
      sa[j9] = __builtin_amdgcn_mfma_f32_16x16x32_bf16(qf[ks], kf, sa[j9], 0, 0, 0);
    }

  const float NINF = -__builtin_inff();
  float mx[4] = {NINF, NINF, NINF, NINF};
#pragma unroll
  for (int j9 = 0; j9 < 9; ++j9) {
    const int s = (w + j9) * 16 + lr;
#pragma unroll
    for (int rr = 0; rr < 4; ++rr) {
      const int qi = w * 16 + lq * 4 + rr;
      const bool valid = (jbase + s >= 0) && (s >= qi) && (s <= qi + 128);
      const float v = valid ? sa[j9][rr] * 0.125f : NINF;
      sa[j9][rr] = v;
      mx[rr] = fmaxf(mx[rr], v);
    }
  }
#pragma unroll
  for (int rr = 0; rr < 4; ++rr)
#pragma unroll
    for (int o = 1; o < 16; o <<= 1) mx[rr] = fmaxf(mx[rr], __shfl_xor(mx[rr], o, 64));
  float sum[4] = {0.f, 0.f, 0.f, 0.f};
#pragma unroll
  for (int j9 = 0; j9 < 9; ++j9)
#pragma unroll
    for (int rr = 0; rr < 4; ++rr) {
      const float p = __expf(sa[j9][rr] - mx[rr]);
      sa[j9][rr] = p;
      sum[rr] += p;
    }
#pragma unroll
  for (int rr = 0; rr < 4; ++rr) {
#pragma unroll
    for (int o = 1; o < 16; o <<= 1) sum[rr] += __shfl_xor(sum[rr], o, 64);
    sum[rr] = 1.0f / sum[rr];
  }
  __syncthreads();  // (2) Ks reads done before Ps overlays

  // write P (9 tiles + 1 zero tile to cover the 160-wide PV window)
#pragma unroll
  for (int j9 = 0; j9 < 9; ++j9) {
    const int jt = w + j9;
#pragma unroll
    for (int rr = 0; rr < 4; ++rr)
      Ps[(w * 16 + lq * 4 + rr) * 200 + jt * 16 + lr] = f2bf(sa[j9][rr] * sum[rr]);
  }
  {
    const int jz = (w == 0) ? 9 : (w == 1) ? 0 : (w == 2) ? 11 : 2;
#pragma unroll
    for (int rr = 0; rr < 4; ++rr) Ps[(w * 16 + lq * 4 + rr) * 200 + jz * 16 + lr] = 0;
  }
  __syncthreads();  // (3) Ps + Vt-half0 ready

  // O = P*V, d-half 0 (output dims 0..31)
  const int W = (w >> 1) * 32;  // halfword offset of the wave's 160-wide window
  const int G0 = W >> 3;
  f32x4 oa[4];
#pragma unroll
  for (int jt = 0; jt < 4; ++jt) oa[jt] = (f32x4){0.f, 0.f, 0.f, 0.f};
#pragma unroll
  for (int ks = 0; ks < 5; ++ks) {
    const bf16x8 pf = *(const bf16x8*)&Ps[(w * 16 + lr) * 200 + W + ks * 32 + lq * 8];
#pragma unroll
    for (int jl = 0; jl < 2; ++jl) {
      const int rl = jl * 16 + lr;
      const int g = G0 + ks * 4 + lq;
      const bf16x8 vf = *(const bf16x8*)&Vt[rl * 200 + ((g ^ (rl >> 3)) << 3)];
      oa[jl] = __builtin_amdgcn_mfma_f32_16x16x32_bf16(pf, vf, oa[jl], 0, 0, 0);
    }
  }
#pragma unroll
  for (int jt = 0; jt < 2; ++jt)
#pragma unroll
    for (int rr = 0; rr < 4; ++rr)
      loc[(size_t)(b * 1024 + i0 + w * 16 + lq * 4 + rr) * 1024 + h * 64 + jt * 16 + lr] =
          f2bf(oa[jt][rr]);
  __syncthreads();  // (4) Vt-half0 reads done

  // write Vt half1 (d>=32)
  if (dh1) {
    const int d0 = (lane & 7) * 8 - 32;  // 0..24 local
#pragma unroll
    for (int c = 0; c < 6; ++c) {
      const int s = (c * 256 + tid) >> 3;
      const int sc = (((s >> 3) ^ j3) << 3) + (s & 7);
      const u32x4 val = vreg[c];
#pragma unroll
      for (int q = 0; q < 4; ++q) {
        Vt[(d0 + 2 * q) * 200 + sc] = (u16)(val[q] & 0xffffu);
        Vt[(d0 + 2 * q + 1) * 200 + sc] = (u16)(val[q] >> 16);
      }
    }
  }
  __syncthreads();  // (5) Vt-half1 ready

  // O = P*V, d-half 1 (output dims 32..63)
#pragma unroll
  for (int ks = 0; ks < 5; ++ks) {
    const bf16x8 pf = *(const bf16x8*)&Ps[(w * 16 + lr) * 200 + W + ks * 32 + lq * 8];
#pragma unroll
    for (int jl = 0; jl < 2; ++jl) {
      const int rl = jl * 16 + lr;
      const int g = G0 + ks * 4 + lq;
      const bf16x8 vf = *(const bf16x8*)&Vt[rl * 200 + ((g ^ (rl >> 3)) << 3)];
      oa[2 + jl] = __builtin_amdgcn_mfma_f32_16x16x32_bf16(pf, vf, oa[2 + jl], 0, 0, 0);
    }
  }
#pragma unroll
  for (int jt = 2; jt < 4; ++jt)
#pragma unroll
    for (int rr = 0; rr < 4; ++rr)
      loc[(size_t)(b * 1024 + i0 + w * 16 + lq * 4 + rr) * 1024 + h * 64 + jt * 16 + lr] =
          f2bf(oa[jt][rr]);

  // ===== compressed-KV phase (reuses qf; overlays Ps region) =====
  __syncthreads();  // (6) Ps reads done
#pragma unroll
  for (int c2 = 0; c2 < 2; ++c2) {
    const int i2 = c2 * 256 + tid;
    const int r2 = i2 >> 3, o2 = (i2 & 7) * 8;
    *(u32x4*)&Kc[r2 * 72 + o2] = kcreg[c2];
    *(u32x4*)&Vc[r2 * 72 + o2] = vcreg[c2];
  }
  __syncthreads();  // (7)

  f32x4 ca[4];
#pragma unroll
  for (int j = 0; j < 4; ++j) ca[j] = (f32x4){0.f, 0.f, 0.f, 0.f};
#pragma unroll
  for (int ks = 0; ks < 2; ++ks)
#pragma unroll
    for (int j = 0; j < 4; ++j) {
      const bf16x8 kf = *(const bf16x8*)&Kc[(j * 16 + lr) * 72 + ks * 32 + lq * 8];
      ca[j] = __builtin_amdgcn_mfma_f32_16x16x32_bf16(qf[ks], kf, ca[j], 0, 0, 0);
    }
  float mc[4] = {NINF, NINF, NINF, NINF};
#pragma unroll
  for (int j = 0; j < 4; ++j) {
    const int s = j * 16 + lr;
#pragma unroll
    for (int rr = 0; rr < 4; ++rr) {
      const int i = i0 + w * 16 + lq * 4 + rr;
      const bool valid = (s <= i) && (s < 63);
      const float v = valid ? ca[j][rr] * 0.125f : NINF;
      ca[j][rr] = v;
      mc[rr] = fmaxf(mc[rr], v);
    }
  }
#pragma unroll
  for (int rr = 0; rr < 4; ++rr)
#pragma unroll
    for (int o = 1; o < 16; o <<= 1) mc[rr] = fmaxf(mc[rr], __shfl_xor(mc[rr], o, 64));
  float sc[4] = {0.f, 0.f, 0.f, 0.f};
#pragma unroll
  for (int j = 0; j < 4; ++j)
#pragma unroll
    for (int rr = 0; rr < 4; ++rr) {
      const float p = __expf(ca[j][rr] - mc[rr]);
      ca[j][rr] = p;
      sc[rr] += p;
    }
#pragma unroll
  for (int rr = 0; rr < 4; ++rr) {
#pragma unroll
    for (int o = 1; o < 16; o <<= 1) sc[rr] += __shfl_xor(sc[rr], o, 64);
    sc[rr] = 1.0f / sc[rr];
  }
#pragma unroll
  for (int j = 0; j < 4; ++j)
#pragma unroll
    for (int rr = 0; rr < 4; ++rr)
      Pc[(w * 16 + lq * 4 + rr) * 72 + j * 16 + lr] = f2bf(ca[j][rr] * sc[rr]);
  __syncthreads();  // (8)

  f32x4 co[4];
#pragma unroll
  for (int jt = 0; jt < 4; ++jt) co[jt] = (f32x4){0.f, 0.f, 0.f, 0.f};
#pragma unroll
  for (int ks = 0; ks < 2; ++ks) {
    const bf16x8 pf = *(const bf16x8*)&Pc[(w * 16 + lr) * 72 + ks * 32 + lq * 8];
#pragma unroll
    for (int jt = 0; jt < 4; ++jt) {
      const bf16x8 vf = *(const bf16x8*)&Vc[(jt * 16 + lr) * 72 + ks * 32 + lq * 8];
      co[jt] = __builtin_amdgcn_mfma_f32_16x16x32_bf16(pf, vf, co[jt], 0, 0, 0);
    }
  }
#pragma unroll
  for (int jt = 0; jt < 4; ++jt)
#pragma unroll
    for (int rr = 0; rr < 4; ++rr)
      outc[(size_t)(b * 1024 + i0 + w * 16 + lq * 4 + rr) * 1024 + h * 64 + jt * 16 + lr] =
          f2bf(co[jt][rr]);
}

// ---------- gating GEMV (round-4: LN of local last rows folded in) ----------
// hraw[b,o] = feats[b,:] . w1[o,:]  where feats = [LN(loc_last) | comp_last].
// Each block recomputes the 8 LN stats (16KB L2-hot reads, cheap redundancy);
// this removes the ln_feats kernel + feats round-trip.
__global__ __launch_bounds__(256) void gate_gemv(const u16* __restrict__ locb,
                                                 const u16* __restrict__ compb,
                                                 const float* __restrict__ lnw,
                                                 const float* __restrict__ w1,
                                                 float* __restrict__ hraw) {
  __shared__ float sm[8], sinv[8];
  const int tid = threadIdx.x;
  const int w = tid >> 6, lane = tid & 63;
  // phase 1: LN stats of the 8 last-token local rows (wave w -> b = w, w+4)
  for (int bb = w; bb < 8; bb += 4) {
    const u16* rp = &locb[((size_t)bb * 1024 + 1023) * 1024 + lane * 16];
    const u32x4 a0 = *(const u32x4*)rp;
    const u32x4 a1 = *(const u32x4*)(rp + 8);
    float s = 0.f, s2 = 0.f;
#pragma unroll
    for (int q = 0; q < 4; ++q) {
      const float x0 = bflo(a0[q]), x1 = bfhi(a0[q]);
      const float x2 = bflo(a1[q]), x3 = bfhi(a1[q]);
      s += x0 + x1 + x2 + x3;
      s2 += x0 * x0 + x1 * x1 + x2 * x2 + x3 * x3;
    }
    s = wredsum(s);
    s2 = wredsum(s2);
    if (!lane) {
      const float m = s * (1.f / 1024.f);
      sm[bb] = m;
      sinv[bb] = rsqrtf(s2 * (1.f / 1024.f) - m * m + 1e-5f);
    }
  }
  __syncthreads();

  const int o = blockIdx.x * 4 + w;
  const float* wr = &w1[(size_t)o * 2048];
  float acc[8] = {};
#pragma unroll
  for (int it = 0; it < 4; ++it) {     // c in [0,1024): LN(local) on the fly
    const int c = (it * 64 + lane) * 4;
    const f32x4 wv = *(const f32x4*)&wr[c];
    const f32x4 lw = *(const f32x4*)&lnw[c];
#pragma unroll
    for (int b = 0; b < 8; ++b) {
      const f32x4 xv = unpack_bf4(*(const u32x2*)&locb[((size_t)b * 1024 + 1023) * 1024 + c]);
      const float mb = sm[b], ib = sinv[b];
      acc[b] += ((xv[0] - mb) * ib * lw[0]) * wv[0] + ((xv[1] - mb) * ib * lw[1]) * wv[1] +
                ((xv[2] - mb) * ib * lw[2]) * wv[2] + ((xv[3] - mb) * ib * lw[3]) * wv[3];
    }
  }
#pragma unroll
  for (int it = 4; it < 8; ++it) {     // c in [1024,2048): comp raw
    const int c = (it * 64 + lane) * 4;
    const f32x4 wv = *(const f32x4*)&wr[c];
    const int c2 = c - 1024;
#pragma unroll
    for (int b = 0; b < 8; ++b) {
      const f32x4 fv = unpack_bf4(*(const u32x2*)&compb[((size_t)b * 1024 + 1023) * 1024 + c2]);
      acc[b] += fv[0] * wv[0] + fv[1] * wv[1] + fv[2] * wv[2] + fv[3] * wv[3];
    }
  }
#pragma unroll
  for (int b = 0; b < 8; ++b) acc[b] = wredsum(acc[b]);
  if (lane == 0) {
#pragma unroll
    for (int b = 0; b < 8; ++b) hraw[b * 1024 + o] = acc[b];
  }
}

// ---------- gating finalize: LN + ReLU + 2-way GEMV + softmax ----------
__global__ __launch_bounds__(256) void gate_fin(const float* __restrict__ hraw,
                                                const float* __restrict__ lnw,
                                                const float* __restrict__ w2,
                                                float* __restrict__ gates) {
  const int b = blockIdx.x, tid = threadIdx.x;
  const f32x4 v = *(const f32x4*)&hraw[(size_t)b * 1024 + tid * 4];
  float s = v[0] + v[1] + v[2] + v[3];
  float s2 = v[0] * v[0] + v[1] * v[1] + v[2] * v[2] + v[3] * v[3];
  s = wredsum(s);
  s2 = wredsum(s2);
  __shared__ float rs[4], rs2[4];
  const int w = tid >> 6, lane = tid & 63;
  if (!lane) { rs[w] = s; rs2[w] = s2; }
  __syncthreads();
  s = rs[0] + rs[1] + rs[2] + rs[3];
  s2 = rs2[0] + rs2[1] + rs2[2] + rs2[3];
  const float m = s * (1.f / 1024.f);
  const float inv = rsqrtf(s2 * (1.f / 1024.f) - m * m + 1e-5f);
  float p0 = 0.f, p1 = 0.f;
#pragma unroll
  for (int k = 0; k < 4; ++k) {
    float hh = (v[k] - m) * inv * lnw[tid * 4 + k];
    hh = fmaxf(hh, 0.f);
    p0 += hh * w2[tid * 4 + k];
    p1 += hh * w2[1024 + tid * 4 + k];
  }
  p0 = wredsum(p0);
  p1 = wredsum(p1);
  __syncthreads();
  if (!lane) { rs[w] = p0; rs2[w] = p1; }
  __syncthreads();
  if (tid == 0) {
    const float l0 = rs[0] + rs[1] + rs[2] + rs[3];
    const float l1 = rs2[0] + rs2[1] + rs2[2] + rs2[3];
    const float mm = fmaxf(l0, l1);
    const float e0 = __expf(l0 - mm), e1 = __expf(l1 - mm);
    const float iv = 1.f / (e0 + e1);
    gates[b * 2] = e0 * iv;
    gates[b * 2 + 1] = e1 * iv;
  }
}

// ---------- fused: per-row LN of local_out + gate-combine + bf16 cast ----------
__global__ __launch_bounds__(256) void combine_ln_cast(const u16* __restrict__ locb,
                                                       const u16* __restrict__ compb,
                                                       const float* __restrict__ lnw,
                                                       const float* __restrict__ gates,
                                                       u16* __restrict__ outb) {
  const int row = blockIdx.x, tid = threadIdx.x;
  const size_t base = (size_t)row * 1024 + tid * 4;
  const f32x4 v = unpack_bf4(*(const u32x2*)&locb[base]);
  float s = v[0] + v[1] + v[2] + v[3];
  float s2 = v[0] * v[0] + v[1] * v[1] + v[2] * v[2] + v[3] * v[3];
  s = wredsum(s);
  s2 = wredsum(s2);
  __shared__ float rs[4], rs2[4];
  const int w = tid >> 6, lane = tid & 63;
  if (!lane) { rs[w] = s; rs2[w] = s2; }
  __syncthreads();
  s = rs[0] + rs[1] + rs[2] + rs[3];
  s2 = rs2[0] + rs2[1] + rs2[2] + rs2[3];
  const float m = s * (1.f / 1024.f);
  const float inv = rsqrtf(s2 * (1.f / 1024.f) - m * m + 1e-5f);
  const int b = row >> 10;
  const float g0 = gates[2 * b], g1 = gates[2 * b + 1];
  const f32x4 wv = *(const f32x4*)&lnw[tid * 4];
  const f32x4 c = unpack_bf4(*(const u32x2*)&compb[base]);
  float ov[4];
#pragma unroll
  for (int k = 0; k < 4; ++k) ov[k] = g0 * ((v[k] - m) * inv * wv[k]) + g1 * c[k];
  u32x2 r;
  r[0] = (u32)f2bf(ov[0]) | ((u32)f2bf(ov[1]) << 16);
  r[1] = (u32)f2bf(ov[2]) | ((u32)f2bf(ov[3]) << 16);
  *(u32x2*)&outb[base] = r;
}

// ---------- launcher ----------
extern "C" void kernel_launch(void* const* d_in, const int* in_sizes, int n_in,
                              void* d_out, int out_size, void* d_ws, size_t ws_size,
                              hipStream_t stream) {
  const float* x = (const float*)d_in[0];
  const float* c_attn_w = (const float*)d_in[1];
  const float* conv_w = (const float*)d_in[2];
  const float* ln_comp_w = (const float*)d_in[3];
  const float* ln_local_w = (const float*)d_in[4];
  const float* gate_w1 = (const float*)d_in[5];
  const float* gate_ln_w = (const float*)d_in[6];
  const float* gate_w2 = (const float*)d_in[7];
  const float* c_proj_w = (const float*)d_in[8];
  float* y = (float*)d_out;

  char* ws = (char*)d_ws;
  size_t off = 0;
  auto alloc = [&](size_t bytes) -> void* {
    void* p = ws + off;
    off += (bytes + 255) & ~(size_t)255;
    return p;
  };
  u16* qkvb = (u16*)alloc((size_t)8192 * 3072 * 2);
  u16* xb = (u16*)alloc((size_t)8192 * 1024 * 2);
  u16* wab = (u16*)alloc((size_t)3072 * 1024 * 2);
  u16* wpb = (u16*)alloc((size_t)1024 * 1024 * 2);
  u16* wcb = (u16*)alloc((size_t)64 * 2048 * 2);
  u16* kcb = (u16*)alloc((size_t)128 * 4096 * 2);  // [bh][nb(64)][d] bf16
  u16* vcb = (u16*)alloc((size_t)128 * 4096 * 2);  // [bh][d][nb(64)] bf16
  u16* locb = (u16*)alloc((size_t)8192 * 1024 * 2);
  u16* compb = (u16*)alloc((size_t)8192 * 1024 * 2);
  float* hraw = (float*)alloc((size_t)8192 * 4);
  float* gates = (float*)alloc(64);
  u16* combb = (u16*)alloc((size_t)8192 * 1024 * 2);

  fused_cast<<<12801, 256, 0, stream>>>(x, c_attn_w, c_proj_w, conv_w, xb, wab, wpb, wcb, kcb,
                                        vcb);

  gemm_bt<1><<<1536, 256, 0, stream>>>(xb, wab, qkvb, 8192, 3072, 1024);

  compress_kernel<<<dim3(252, 2), 256, 0, stream>>>(qkvb, wcb, ln_comp_w, kcb, vcb);

  attn_fused<<<dim3(128, 16), 256, 0, stream>>>(qkvb, kcb, vcb, locb, compb);

  gate_gemv<<<256, 256, 0, stream>>>(locb, compb, ln_local_w, gate_w1, hraw);
  gate_fin<<<8, 256, 0, stream>>>(hraw, gate_ln_w, gate_w2, gates);

  combine_ln_cast<<<8192, 256, 0, stream>>>(locb, compb, ln_local_w, gates, combb);

  gemm_bt<0><<<512, 256, 0, stream>>>(combb, wpb, y, 8192, 1024, 1024);
}

// Round 5
// 282.121 us; speedup vs baseline: 1.0454x; 1.0454x over previous
//
#include <hip/hip_runtime.h>
#include <cstdint>
#include <cmath>
#include <cstddef>

typedef unsigned int u32;
typedef unsigned short u16;
typedef __bf16 bf16x8 __attribute__((ext_vector_type(8)));
typedef float f32x4 __attribute__((ext_vector_type(4)));
typedef u32 u32x4 __attribute__((ext_vector_type(4)));
typedef u32 u32x2 __attribute__((ext_vector_type(2)));

#define DEV static __device__ __forceinline__

// ---------- helpers ----------
DEV float bflo(u32 u) { return __uint_as_float(u << 16); }
DEV float bfhi(u32 u) { return __uint_as_float(u & 0xffff0000u); }
DEV u16 f2bf(float f) {               // RNE fp32 -> bf16
  u32 u = __float_as_uint(f);
  u += 0x7fffu + ((u >> 16) & 1u);
  return (u16)(u >> 16);
}
DEV f32x4 unpack_bf4(u32x2 r) {
  return (f32x4){bflo(r[0]), bfhi(r[0]), bflo(r[1]), bfhi(r[1])};
}
DEV float wredsum(float v) {
#pragma unroll
  for (int o = 32; o; o >>= 1) v += __shfl_xor(v, o, 64);
  return v;
}

// async global->LDS, 16B per lane. LDS dest is wave-uniform base + lane*16.
DEV void gload_lds16(const u16* g, u16* lds_base) {
  __builtin_amdgcn_global_load_lds((const __attribute__((address_space(1))) void*)g,
                                   (__attribute__((address_space(3))) void*)lds_base,
                                   16, 0, 0);
}

// ---------- fused casts + workspace pad zeroing ----------
__global__ __launch_bounds__(256) void fused_cast(const float* __restrict__ x,
                                                  const float* __restrict__ aw,
                                                  const float* __restrict__ pw,
                                                  const float* __restrict__ cw,
                                                  u16* __restrict__ xb,
                                                  u16* __restrict__ wab,
                                                  u16* __restrict__ wpb,
                                                  u16* __restrict__ wcb,
                                                  u16* __restrict__ kcb,
                                                  u16* __restrict__ vcb) {
  const int blk = blockIdx.x;
  if (blk < 12288) {
    const float* src;
    u16* dst;
    int base;
    if (blk < 8192) { src = x; dst = xb; base = blk; }
    else if (blk < 11264) { src = aw; dst = wab; base = blk - 8192; }
    else { src = pw; dst = wpb; base = blk - 11264; }
    const size_t idx = ((size_t)base * 256 + threadIdx.x) * 4;
    const f32x4 v = *(const f32x4*)&src[idx];
    u32x2 r;
    r[0] = (u32)f2bf(v[0]) | ((u32)f2bf(v[1]) << 16);
    r[1] = (u32)f2bf(v[2]) | ((u32)f2bf(v[3]) << 16);
    *(u32x2*)&dst[idx] = r;
  } else if (blk < 12800) {
    // conv_w [64][64][32] (o,i,kk) fp32 -> Wc[o][kk*64+i] bf16
    const int idx = (blk - 12288) * 256 + threadIdx.x;
    const int o = idx >> 11;
    const int rest = idx & 2047;
    const int i = rest >> 5;
    const int kk = rest & 31;
    wcb[(o << 11) + (kk << 6) + i] = f2bf(cw[idx]);
  } else {
    for (int i = threadIdx.x; i < 8192; i += 256) {
      const int bh = i >> 6, d = i & 63;
      kcb[bh * 4096 + 63 * 64 + d] = 0;   // K-block row 63 (pad)
      vcb[bh * 4096 + d * 64 + 63] = 0;   // V col 63 (pad)
    }
  }
}

// ---------- MFMA GEMM: out[M,N] = A[M,K](bf16) * B[N,K](bf16)^T ----------
// 128x128 tile, BK=64, 256 threads; global_load_lds width=16.
// XOR-swizzled LDS. At the m97-structure ceiling (~935 TF).
// NOTE (round-1): 8-phase port without full derived-waits regressed (567 TF).
// NOTE (round-4): XCD-chunk swizzle regressed 4.3x FETCH — the default x-fast
// 2-D dispatch already gives each XCD only ~8 A-row tiles (2MB, L2-fit) x 16
// B-panels (4MB); chunking blew the A working set to 16MB/XCD. Keep 2-D grid.
template <int OUT_BF16>
__global__ __launch_bounds__(256, 4) void gemm_bt(const u16* __restrict__ A,
                                                  const u16* __restrict__ Bm,
                                                  void* __restrict__ out,
                                                  int M, int N, int K) {
  __shared__ u16 As[128 * 64];
  __shared__ u16 Bs[128 * 64];
  const int tid = threadIdx.x;
  const int lane = tid & 63;
  const int w = tid >> 6;
  const int row0 = blockIdx.x * 128;
  const int col0 = blockIdx.y * 128;
  const int wm = (w >> 1) * 64, wn = (w & 1) * 64;
  const int lr = lane & 15, lq = lane >> 4;
  const int srow = lane >> 3;
  const int scol = ((lane & 7) ^ (srow & 7)) * 8;
  const int pgA = ((lq ^ (lr & 7)) * 8);  // ks=0; ks=1 is pgA ^ 32

  f32x4 acc[4][4] = {};

  for (int k0 = 0; k0 < K; k0 += 64) {
    __syncthreads();
#pragma unroll
    for (int c = 0; c < 4; ++c) {
      const int base_r = w * 32 + c * 8;   // wave-uniform
      gload_lds16(&A[(size_t)(row0 + base_r + srow) * K + k0 + scol], &As[base_r * 64]);
      gload_lds16(&Bm[(size_t)(col0 + base_r + srow) * K + k0 + scol], &Bs[base_r * 64]);
    }
    __syncthreads();
#pragma unroll
    for (int ks = 0; ks < 2; ++ks) {
      const int pg = pgA ^ (ks << 5);
      bf16x8 af[4], bfr[4];
#pragma unroll
      for (int i = 0; i < 4; ++i) {
        af[i] = *(const bf16x8*)&As[(wm + i * 16 + lr) * 64 + pg];
        bfr[i] = *(const bf16x8*)&Bs[(wn + i * 16 + lr) * 64 + pg];
      }
#pragma unroll
      for (int i = 0; i < 4; ++i)
#pragma unroll
        for (int j = 0; j < 4; ++j)
          acc[i][j] = __builtin_amdgcn_mfma_f32_16x16x32_bf16(af[i], bfr[j], acc[i][j], 0, 0, 0);
    }
  }
#pragma unroll
  for (int i = 0; i < 4; ++i)
#pragma unroll
    for (int j = 0; j < 4; ++j)
#pragma unroll
      for (int rr = 0; rr < 4; ++rr) {
        const int gr = row0 + wm + i * 16 + lq * 4 + rr;
        const int gc = col0 + wn + j * 16 + lr;
        const float v = acc[i][j][rr];
        if (OUT_BF16)
          ((u16*)out)[(size_t)gr * N + gc] = f2bf(v);
        else
          ((float*)out)[(size_t)gr * N + gc] = v;
      }
}

// ---------- compression: conv(K=32,stride16) as GEMM + LN(64) + GELU ----------
// BM=32 tiles, grid (252, 2); BK=128 double-buffered (round-2 win).
__global__ __launch_bounds__(256) void compress_kernel(const u16* __restrict__ qkv,
                                                       const u16* __restrict__ Wc,
                                                       const float* __restrict__ ln_w,
                                                       u16* __restrict__ kcb,
                                                       u16* __restrict__ vcb) {
  __shared__ u16 As[2][32 * 128];   // 16 KB
  __shared__ u16 Bs[2][64 * 128];   // 32 KB
  __shared__ float Cs[32][65];      // 8.3 KB
  const int tid = threadIdx.x;
  const int lane = tid & 63, w = tid >> 6;
  const int lr = lane & 15, lq = lane >> 4;
  const int r0 = blockIdx.x * 32;
  const int srcoff = 1024 + (int)blockIdx.y * 1024;

  size_t abase[2];
#pragma unroll
  for (int g2 = 0; g2 < 2; ++g2) {
    const int r = 8 * w + 4 * g2 + (lane >> 4);       // 0..31
    const int gr = r0 + r;
    const int bh = gr / 63;
    const int nb = gr - bh * 63;
    const int b = bh >> 4, h = bh & 15;
    const int jbit = (lane >> 3) & 1;                 // L>>3
    const int icol = ((lane & 7) ^ (r & 7)) * 8;      // (L&7)*8
    abase[g2] = (size_t)(b * 1024 + nb * 16 + jbit) * 3072 + srcoff + h * 64 + icol;
  }
  size_t bbase[4];
#pragma unroll
  for (int c = 0; c < 4; ++c) {
    const int rB = 16 * w + 4 * c + (lane >> 4);      // 0..63
    const int Lcol = (((lane & 7) ^ (rB & 7)) | (lane & 8)) * 8;
    bbase[c] = (size_t)rB * 2048 + Lcol;
  }

  auto stage = [&](int it, int bs) {
#pragma unroll
    for (int g2 = 0; g2 < 2; ++g2)
      gload_lds16(&qkv[abase[g2] + (size_t)it * 6144], &As[bs][(8 * w + 4 * g2) * 128]);
#pragma unroll
    for (int c = 0; c < 4; ++c)
      gload_lds16(&Wc[bbase[c] + (size_t)it * 128], &Bs[bs][(16 * w + 4 * c) * 128]);
  };

  const int rw = (w & 1) * 16;   // row-half this wave computes
  const int cw = (w >> 1) * 32;  // col-half this wave computes
  f32x4 acc[2] = {};

  stage(0, 0);
  for (int it = 0; it < 16; ++it) {
    const int cur = it & 1;
    __syncthreads();               // drains stage for buf cur
    if (it < 15) stage(it + 1, cur ^ 1);
    const int rowA = rw + lr;
#pragma unroll
    for (int ks = 0; ks < 4; ++ks) {
      const int L = ks * 4 + lq;                       // logical 8-hw group 0..15
      const int pgA = (((L & 7) ^ (rowA & 7)) | (L & 8)) * 8;
      const bf16x8 af = *(const bf16x8*)&As[cur][rowA * 128 + pgA];
#pragma unroll
      for (int j = 0; j < 2; ++j) {
        const int rowB = cw + j * 16 + lr;
        const int pgB = (((L & 7) ^ (rowB & 7)) | (L & 8)) * 8;
        const bf16x8 bfr = *(const bf16x8*)&Bs[cur][rowB * 128 + pgB];
        acc[j] = __builtin_amdgcn_mfma_f32_16x16x32_bf16(af, bfr, acc[j], 0, 0, 0);
      }
    }
  }
  __syncthreads();
#pragma unroll
  for (int j = 0; j < 2; ++j)
#pragma unroll
    for (int rr = 0; rr < 4; ++rr)
      Cs[rw + lq * 4 + rr][cw + j * 16 + lr] = acc[j][rr];
  __syncthreads();
  if (tid < 32) {
    const int gr2 = r0 + tid;
    const int bh2 = gr2 / 63;
    const int nb2 = gr2 - bh2 * 63;
    float s = 0.f, s2 = 0.f;
#pragma unroll 8
    for (int d = 0; d < 64; ++d) {
      const float xv = Cs[tid][d];
      s += xv;
      s2 += xv * xv;
    }
    const float m = s * (1.f / 64.f);
    const float inv = rsqrtf(s2 * (1.f / 64.f) - m * m + 1e-5f);
    if (blockIdx.y == 0) {
      const size_t gb = (size_t)bh2 * 4096 + nb2 * 64;
#pragma unroll 8
      for (int d = 0; d < 64; ++d) {
        const float z = (Cs[tid][d] - m) * inv * ln_w[d];
        kcb[gb + d] = f2bf(0.5f * z * (1.f + erff(z * 0.70710678118f)));
      }
    } else {
      const size_t gb = (size_t)bh2 * 4096 + nb2;
#pragma unroll 8
      for (int d = 0; d < 64; ++d) {
        const float z = (Cs[tid][d] - m) * inv * ln_w[d];
        vcb[gb + d * 64] = f2bf(0.5f * z * (1.f + erff(z * 0.70710678118f)));
      }
    }
  }
}

// ---------- fused attention: local banded (window 129) + compressed-KV ----------
// grid (B*H, T/64); block 256 = 4 waves; wave w owns query rows w*16..w*16+15.
// Round-3: swizzled Vt (bank-conflict fix), [32][200] d-half ping-pong
// (LDS 40448 -> 4 blocks/CU), reg-prefetched Kc/Vc (T14).
__global__ __launch_bounds__(256, 4) void attn_fused(const u16* __restrict__ qkv,
                                                     const u16* __restrict__ kcb,
                                                     const u16* __restrict__ vcb,
                                                     u16* __restrict__ loc,
                                                     u16* __restrict__ outc) {
  __shared__ __align__(16) char smem[40448];
  u16* Ks = (u16*)smem;            // [192][72] bf16, local QK phase (27648 B)
  u16* Ps = (u16*)smem;            // [64][200] bf16, overlays Ks after QK (25600 B)
  u16* Vt = (u16*)(smem + 27648);  // [32][200] bf16, swizzled d-half ping-pong
  u16* Kc = (u16*)smem;            // [64][72] compressed phase
  u16* Vc = (u16*)(smem + 9216);   // [64][72]
  u16* Pc = (u16*)(smem + 18432);  // [64][72]
  const int bh = blockIdx.x;
  const int b = bh >> 4, h = bh & 15;
  const int i0 = blockIdx.y * 64;
  const int jbase = i0 - 128;
  const int tid = threadIdx.x;
  const int lane = tid & 63, w = tid >> 6;
  const int lr = lane & 15, lq = lane >> 4;
  const int j3 = lane & 3;            // (Vt local row)>>3 for this lane's dims
  const int dh1 = (lane >> 2) & 1;    // 1 if this lane's V dims are >= 32

  // stage K into LDS, V into regs; Q fragments from global
  u32x4 vreg[6];
#pragma unroll
  for (int c = 0; c < 6; ++c) {
    const int lin = c * 256 + tid;
    const int s = lin >> 3, d0 = (lin & 7) * 8;
    const int j = jbase + s;
    u32x4 kval = {0, 0, 0, 0}, vval = {0, 0, 0, 0};
    if (j >= 0) {
      const size_t ro = (size_t)(b * 1024 + j) * 3072 + h * 64 + d0;
      kval = *(const u32x4*)&qkv[ro + 1024];
      vval = *(const u32x4*)&qkv[ro + 2048];
    }
    vreg[c] = vval;
    *(u32x4*)&Ks[s * 72 + d0] = kval;
  }
  // write Vt half0 (d<32) now: region disjoint from Ks, barrier (1) covers it
  if (!dh1) {
    const int d0 = (lane & 7) * 8;    // 0..24
#pragma unroll
    for (int c = 0; c < 6; ++c) {
      const int s = (c * 256 + tid) >> 3;
      const int sc = (((s >> 3) ^ j3) << 3) + (s & 7);
      const u32x4 val = vreg[c];
#pragma unroll
      for (int q = 0; q < 4; ++q) {
        Vt[(d0 + 2 * q) * 200 + sc] = (u16)(val[q] & 0xffffu);
        Vt[(d0 + 2 * q + 1) * 200 + sc] = (u16)(val[q] >> 16);
      }
    }
  }
  bf16x8 qf[2];
  {
    const size_t qrow = (size_t)(b * 1024 + i0 + w * 16 + lr) * 3072 + h * 64;
#pragma unroll
    for (int ks = 0; ks < 2; ++ks) qf[ks] = *(const bf16x8*)&qkv[qrow + ks * 32 + lq * 8];
  }
  // T14: prefetch compressed K/V (L2-resident) for phase 2
  const size_t cb = (size_t)bh * 4096;
  u32x4 kcreg[2], vcreg[2];
#pragma unroll
  for (int c2 = 0; c2 < 2; ++c2) {
    const int i2 = c2 * 256 + tid;
    const size_t o2 = (size_t)(i2 >> 3) * 64 + (i2 & 7) * 8;
    kcreg[c2] = *(const u32x4*)&kcb[cb + o2];
    vcreg[c2] = *(const u32x4*)&vcb[cb + o2];
  }
  __syncthreads();  // (1) Ks + Vt-half0 visible

  // S = Q*K^T over the 9 band tiles jt = w..w+8
  f32x4 sa[9];
#pragma unroll
  for (int j9 = 0; j9 < 9; ++j9) sa[j9] = (f32x4){0.f, 0.f, 0.f, 0.f};
#pragma unroll
  for (int ks = 0; ks < 2; ++ks)
#pragma unroll
    for (int j9 = 0; j9 < 9; ++j9) {
      const int jt = w + j9;
      const bf16x8 kf = *(const bf16x8*)&Ks[(jt * 16 + lr) * 72 + ks * 32 + lq * 8];
      sa[j9] = __builtin_amdgcn_mfma_f32_16x16x32_bf16(qf[ks], kf, sa[j9], 0, 0, 0);
    }

  const float NINF = -__builtin_inff();
  float mx[4] = {NINF, NINF, NINF, NINF};
#pragma unroll
  for (int j9 = 0; j9 < 9; ++j9) {
    const int s = (w + j9) * 16 + lr;
#pragma unroll
    for (int rr = 0; rr < 4; ++rr) {
      const int qi = w * 16 + lq * 4 + rr;
      const bool valid = (jbase + s >= 0) && (s >= qi) && (s <= qi + 128);
      const float v = valid ? sa[j9][rr] * 0.125f : NINF;
      sa[j9][rr] = v;
      mx[rr] = fmaxf(mx[rr], v);
    }
  }
#pragma unroll
  for (int rr = 0; rr < 4; ++rr)
#pragma unroll
    for (int o = 1; o < 16; o <<= 1) mx[rr] = fmaxf(mx[rr], __shfl_xor(mx[rr], o, 64));
  float sum[4] = {0.f, 0.f, 0.f, 0.f};
#pragma unroll
  for (int j9 = 0; j9 < 9; ++j9)
#pragma unroll
    for (int rr = 0; rr < 4; ++rr) {
      const float p = __expf(sa[j9][rr] - mx[rr]);
      sa[j9][rr] = p;
      sum[rr] += p;
    }
#pragma unroll
  for (int rr = 0; rr < 4; ++rr) {
#pragma unroll
    for (int o = 1; o < 16; o <<= 1) sum[rr] += __shfl_xor(sum[rr], o, 64);
    sum[rr] = 1.0f / sum[rr];
  }
  __syncthreads();  // (2) Ks reads done before Ps overlays

  // write P (9 tiles + 1 zero tile to cover the 160-wide PV window)
#pragma unroll
  for (int j9 = 0; j9 < 9; ++j9) {
    const int jt = w + j9;
#pragma unroll
    for (int rr = 0; rr < 4; ++rr)
      Ps[(w * 16 + lq * 4 + rr) * 200 + jt * 16 + lr] = f2bf(sa[j9][rr] * sum[rr]);
  }
  {
    const int jz = (w == 0) ? 9 : (w == 1) ? 0 : (w == 2) ? 11 : 2;
#pragma unroll
    for (int rr = 0; rr < 4; ++rr) Ps[(w * 16 + lq * 4 + rr) * 200 + jz * 16 + lr] = 0;
  }
  __syncthreads();  // (3) Ps + Vt-half0 ready

  // O = P*V, d-half 0 (output dims 0..31)
  const int W = (w >> 1) * 32;  // halfword offset of the wave's 160-wide window
  const int G0 = W >> 3;
  f32x4 oa[4];
#pragma unroll
  for (int jt = 0; jt < 4; ++jt) oa[jt] = (f32x4){0.f, 0.f, 0.f, 0.f};
#pragma unroll
  for (int ks = 0; ks < 5; ++ks) {
    const bf16x8 pf = *(const bf16x8*)&Ps[(w * 16 + lr) * 200 + W + ks * 32 + lq * 8];
#pragma unroll
    for (int jl = 0; jl < 2; ++jl) {
      const int rl = jl * 16 + lr;
      const int g = G0 + ks * 4 + lq;
      const bf16x8 vf = *(const bf16x8*)&Vt[rl * 200 + ((g ^ (rl >> 3)) << 3)];
      oa[jl] = __builtin_amdgcn_mfma_f32_16x16x32_bf16(pf, vf, oa[jl], 0, 0, 0);
    }
  }
#pragma unroll
  for (int jt = 0; jt < 2; ++jt)
#pragma unroll
    for (int rr = 0; rr < 4; ++rr)
      loc[(size_t)(b * 1024 + i0 + w * 16 + lq * 4 + rr) * 1024 + h * 64 + jt * 16 + lr] =
          f2bf(oa[jt][rr]);
  __syncthreads();  // (4) Vt-half0 reads done

  // write Vt half1 (d>=32)
  if (dh1) {
    const int d0 = (lane & 7) * 8 - 32;  // 0..24 local
#pragma unroll
    for (int c = 0; c < 6; ++c) {
      const int s = (c * 256 + tid) >> 3;
      const int sc = (((s >> 3) ^ j3) << 3) + (s & 7);
      const u32x4 val = vreg[c];
#pragma unroll
      for (int q = 0; q < 4; ++q) {
        Vt[(d0 + 2 * q) * 200 + sc] = (u16)(val[q] & 0xffffu);
        Vt[(d0 + 2 * q + 1) * 200 + sc] = (u16)(val[q] >> 16);
      }
    }
  }
  __syncthreads();  // (5) Vt-half1 ready

  // O = P*V, d-half 1 (output dims 32..63)
#pragma unroll
  for (int ks = 0; ks < 5; ++ks) {
    const bf16x8 pf = *(const bf16x8*)&Ps[(w * 16 + lr) * 200 + W + ks * 32 + lq * 8];
#pragma unroll
    for (int jl = 0; jl < 2; ++jl) {
      const int rl = jl * 16 + lr;
      const int g = G0 + ks * 4 + lq;
      const bf16x8 vf = *(const bf16x8*)&Vt[rl * 200 + ((g ^ (rl >> 3)) << 3)];
      oa[2 + jl] = __builtin_amdgcn_mfma_f32_16x16x32_bf16(pf, vf, oa[2 + jl], 0, 0, 0);
    }
  }
#pragma unroll
  for (int jt = 2; jt < 4; ++jt)
#pragma unroll
    for (int rr = 0; rr < 4; ++rr)
      loc[(size_t)(b * 1024 + i0 + w * 16 + lq * 4 + rr) * 1024 + h * 64 + jt * 16 + lr] =
          f2bf(oa[jt][rr]);

  // ===== compressed-KV phase (reuses qf; overlays Ps region) =====
  __syncthreads();  // (6) Ps reads done
#pragma unroll
  for (int c2 = 0; c2 < 2; ++c2) {
    const int i2 = c2 * 256 + tid;
    const int r2 = i2 >> 3, o2 = (i2 & 7) * 8;
    *(u32x4*)&Kc[r2 * 72 + o2] = kcreg[c2];
    *(u32x4*)&Vc[r2 * 72 + o2] = vcreg[c2];
  }
  __syncthreads();  // (7)

  f32x4 ca[4];
#pragma unroll
  for (int j = 0; j < 4; ++j) ca[j] = (f32x4){0.f, 0.f, 0.f, 0.f};
#pragma unroll
  for (int ks = 0; ks < 2; ++ks)
#pragma unroll
    for (int j = 0; j < 4; ++j) {
      const bf16x8 kf = *(const bf16x8*)&Kc[(j * 16 + lr) * 72 + ks * 32 + lq * 8];
      ca[j] = __builtin_amdgcn_mfma_f32_16x16x32_bf16(qf[ks], kf, ca[j], 0, 0, 0);
    }
  float mc[4] = {NINF, NINF, NINF, NINF};
#pragma unroll
  for (int j = 0; j < 4; ++j) {
    const int s = j * 16 + lr;
#pragma unroll
    for (int rr = 0; rr < 4; ++rr) {
      const int i = i0 + w * 16 + lq * 4 + rr;
      const bool valid = (s <= i) && (s < 63);
      const float v = valid ? ca[j][rr] * 0.125f : NINF;
      ca[j][rr] = v;
      mc[rr] = fmaxf(mc[rr], v);
    }
  }
#pragma unroll
  for (int rr = 0; rr < 4; ++rr)
#pragma unroll
    for (int o = 1; o < 16; o <<= 1) mc[rr] = fmaxf(mc[rr], __shfl_xor(mc[rr], o, 64));
  float sc[4] = {0.f, 0.f, 0.f, 0.f};
#pragma unroll
  for (int j = 0; j < 4; ++j)
#pragma unroll
    for (int rr = 0; rr < 4; ++rr) {
      const float p = __expf(ca[j][rr] - mc[rr]);
      ca[j][rr] = p;
      sc[rr] += p;
    }
#pragma unroll
  for (int rr = 0; rr < 4; ++rr) {
#pragma unroll
    for (int o = 1; o < 16; o <<= 1) sc[rr] += __shfl_xor(sc[rr], o, 64);
    sc[rr] = 1.0f / sc[rr];
  }
#pragma unroll
  for (int j = 0; j < 4; ++j)
#pragma unroll
    for (int rr = 0; rr < 4; ++rr)
      Pc[(w * 16 + lq * 4 + rr) * 72 + j * 16 + lr] = f2bf(ca[j][rr] * sc[rr]);
  __syncthreads();  // (8)

  f32x4 co[4];
#pragma unroll
  for (int jt = 0; jt < 4; ++jt) co[jt] = (f32x4){0.f, 0.f, 0.f, 0.f};
#pragma unroll
  for (int ks = 0; ks < 2; ++ks) {
    const bf16x8 pf = *(const bf16x8*)&Pc[(w * 16 + lr) * 72 + ks * 32 + lq * 8];
#pragma unroll
    for (int jt = 0; jt < 4; ++jt) {
      const bf16x8 vf = *(const bf16x8*)&Vc[(jt * 16 + lr) * 72 + ks * 32 + lq * 8];
      co[jt] = __builtin_amdgcn_mfma_f32_16x16x32_bf16(pf, vf, co[jt], 0, 0, 0);
    }
  }
#pragma unroll
  for (int jt = 0; jt < 4; ++jt)
#pragma unroll
    for (int rr = 0; rr < 4; ++rr)
      outc[(size_t)(b * 1024 + i0 + w * 16 + lq * 4 + rr) * 1024 + h * 64 + jt * 16 + lr] =
          f2bf(co[jt][rr]);
}

// ---------- gating GEMV (round-4: LN of local last rows folded in) ----------
// hraw[b,o] = feats[b,:] . w1[o,:]  where feats = [LN(loc_last) | comp_last].
// Each block recomputes the 8 LN stats (16KB L2-hot reads, cheap redundancy);
// this removes the ln_feats kernel + feats round-trip.
__global__ __launch_bounds__(256) void gate_gemv(const u16* __restrict__ locb,
                                                 const u16* __restrict__ compb,
                                                 const float* __restrict__ lnw,
                                                 const float* __restrict__ w1,
                                                 float* __restrict__ hraw) {
  __shared__ float sm[8], sinv[8];
  const int tid = threadIdx.x;
  const int w = tid >> 6, lane = tid & 63;
  // phase 1: LN stats of the 8 last-token local rows (wave w -> b = w, w+4)
  for (int bb = w; bb < 8; bb += 4) {
    const u16* rp = &locb[((size_t)bb * 1024 + 1023) * 1024 + lane * 16];
    const u32x4 a0 = *(const u32x4*)rp;
    const u32x4 a1 = *(const u32x4*)(rp + 8);
    float s = 0.f, s2 = 0.f;
#pragma unroll
    for (int q = 0; q < 4; ++q) {
      const float x0 = bflo(a0[q]), x1 = bfhi(a0[q]);
      const float x2 = bflo(a1[q]), x3 = bfhi(a1[q]);
      s += x0 + x1 + x2 + x3;
      s2 += x0 * x0 + x1 * x1 + x2 * x2 + x3 * x3;
    }
    s = wredsum(s);
    s2 = wredsum(s2);
    if (!lane) {
      const float m = s * (1.f / 1024.f);
      sm[bb] = m;
      sinv[bb] = rsqrtf(s2 * (1.f / 1024.f) - m * m + 1e-5f);
    }
  }
  __syncthreads();

  const int o = blockIdx.x * 4 + w;
  const float* wr = &w1[(size_t)o * 2048];
  float acc[8] = {};
#pragma unroll
  for (int it = 0; it < 4; ++it) {     // c in [0,1024): LN(local) on the fly
    const int c = (it * 64 + lane) * 4;
    const f32x4 wv = *(const f32x4*)&wr[c];
    const f32x4 lw = *(const f32x4*)&lnw[c];
#pragma unroll
    for (int b = 0; b < 8; ++b) {
      const f32x4 xv = unpack_bf4(*(const u32x2*)&locb[((size_t)b * 1024 + 1023) * 1024 + c]);
      const float mb = sm[b], ib = sinv[b];
      acc[b] += ((xv[0] - mb) * ib * lw[0]) * wv[0] + ((xv[1] - mb) * ib * lw[1]) * wv[1] +
                ((xv[2] - mb) * ib * lw[2]) * wv[2] + ((xv[3] - mb) * ib * lw[3]) * wv[3];
    }
  }
#pragma unroll
  for (int it = 4; it < 8; ++it) {     // c in [1024,2048): comp raw
    const int c = (it * 64 + lane) * 4;
    const f32x4 wv = *(const f32x4*)&wr[c];
    const int c2 = c - 1024;
#pragma unroll
    for (int b = 0; b < 8; ++b) {
      const f32x4 fv = unpack_bf4(*(const u32x2*)&compb[((size_t)b * 1024 + 1023) * 1024 + c2]);
      acc[b] += fv[0] * wv[0] + fv[1] * wv[1] + fv[2] * wv[2] + fv[3] * wv[3];
    }
  }
#pragma unroll
  for (int b = 0; b < 8; ++b) acc[b] = wredsum(acc[b]);
  if (lane == 0) {
#pragma unroll
    for (int b = 0; b < 8; ++b) hraw[b * 1024 + o] = acc[b];
  }
}

// ---------- gating finalize: LN + ReLU + 2-way GEMV + softmax ----------
__global__ __launch_bounds__(256) void gate_fin(const float* __restrict__ hraw,
                                                const float* __restrict__ lnw,
                                                const float* __restrict__ w2,
                                                float* __restrict__ gates) {
  const int b = blockIdx.x, tid = threadIdx.x;
  const f32x4 v = *(const f32x4*)&hraw[(size_t)b * 1024 + tid * 4];
  float s = v[0] + v[1] + v[2] + v[3];
  float s2 = v[0] * v[0] + v[1] * v[1] + v[2] * v[2] + v[3] * v[3];
  s = wredsum(s);
  s2 = wredsum(s2);
  __shared__ float rs[4], rs2[4];
  const int w = tid >> 6, lane = tid & 63;
  if (!lane) { rs[w] = s; rs2[w] = s2; }
  __syncthreads();
  s = rs[0] + rs[1] + rs[2] + rs[3];
  s2 = rs2[0] + rs2[1] + rs2[2] + rs2[3];
  const float m = s * (1.f / 1024.f);
  const float inv = rsqrtf(s2 * (1.f / 1024.f) - m * m + 1e-5f);
  float p0 = 0.f, p1 = 0.f;
#pragma unroll
  for (int k = 0; k < 4; ++k) {
    float hh = (v[k] - m) * inv * lnw[tid * 4 + k];
    hh = fmaxf(hh, 0.f);
    p0 += hh * w2[tid * 4 + k];
    p1 += hh * w2[1024 + tid * 4 + k];
  }
  p0 = wredsum(p0);
  p1 = wredsum(p1);
  __syncthreads();
  if (!lane) { rs[w] = p0; rs2[w] = p1; }
  __syncthreads();
  if (tid == 0) {
    const float l0 = rs[0] + rs[1] + rs[2] + rs[3];
    const float l1 = rs2[0] + rs2[1] + rs2[2] + rs2[3];
    const float mm = fmaxf(l0, l1);
    const float e0 = __expf(l0 - mm), e1 = __expf(l1 - mm);
    const float iv = 1.f / (e0 + e1);
    gates[b * 2] = e0 * iv;
    gates[b * 2 + 1] = e1 * iv;
  }
}

// ---------- fused: per-row LN of local_out + gate-combine + bf16 cast ----------
__global__ __launch_bounds__(256) void combine_ln_cast(const u16* __restrict__ locb,
                                                       const u16* __restrict__ compb,
                                                       const float* __restrict__ lnw,
                                                       const float* __restrict__ gates,
                                                       u16* __restrict__ outb) {
  const int row = blockIdx.x, tid = threadIdx.x;
  const size_t base = (size_t)row * 1024 + tid * 4;
  const f32x4 v = unpack_bf4(*(const u32x2*)&locb[base]);
  float s = v[0] + v[1] + v[2] + v[3];
  float s2 = v[0] * v[0] + v[1] * v[1] + v[2] * v[2] + v[3] * v[3];
  s = wredsum(s);
  s2 = wredsum(s2);
  __shared__ float rs[4], rs2[4];
  const int w = tid >> 6, lane = tid & 63;
  if (!lane) { rs[w] = s; rs2[w] = s2; }
  __syncthreads();
  s = rs[0] + rs[1] + rs[2] + rs[3];
  s2 = rs2[0] + rs2[1] + rs2[2] + rs2[3];
  const float m = s * (1.f / 1024.f);
  const float inv = rsqrtf(s2 * (1.f / 1024.f) - m * m + 1e-5f);
  const int b = row >> 10;
  const float g0 = gates[2 * b], g1 = gates[2 * b + 1];
  const f32x4 wv = *(const f32x4*)&lnw[tid * 4];
  const f32x4 c = unpack_bf4(*(const u32x2*)&compb[base]);
  float ov[4];
#pragma unroll
  for (int k = 0; k < 4; ++k) ov[k] = g0 * ((v[k] - m) * inv * wv[k]) + g1 * c[k];
  u32x2 r;
  r[0] = (u32)f2bf(ov[0]) | ((u32)f2bf(ov[1]) << 16);
  r[1] = (u32)f2bf(ov[2]) | ((u32)f2bf(ov[3]) << 16);
  *(u32x2*)&outb[base] = r;
}

// ---------- launcher ----------
extern "C" void kernel_launch(void* const* d_in, const int* in_sizes, int n_in,
                              void* d_out, int out_size, void* d_ws, size_t ws_size,
                              hipStream_t stream) {
  const float* x = (const float*)d_in[0];
  const float* c_attn_w = (const float*)d_in[1];
  const float* conv_w = (const float*)d_in[2];
  const float* ln_comp_w = (const float*)d_in[3];
  const float* ln_local_w = (const float*)d_in[4];
  const float* gate_w1 = (const float*)d_in[5];
  const float* gate_ln_w = (const float*)d_in[6];
  const float* gate_w2 = (const float*)d_in[7];
  const float* c_proj_w = (const float*)d_in[8];
  float* y = (float*)d_out;

  char* ws = (char*)d_ws;
  size_t off = 0;
  auto alloc = [&](size_t bytes) -> void* {
    void* p = ws + off;
    off += (bytes + 255) & ~(size_t)255;
    return p;
  };
  u16* qkvb = (u16*)alloc((size_t)8192 * 3072 * 2);
  u16* xb = (u16*)alloc((size_t)8192 * 1024 * 2);
  u16* wab = (u16*)alloc((size_t)3072 * 1024 * 2);
  u16* wpb = (u16*)alloc((size_t)1024 * 1024 * 2);
  u16* wcb = (u16*)alloc((size_t)64 * 2048 * 2);
  u16* kcb = (u16*)alloc((size_t)128 * 4096 * 2);  // [bh][nb(64)][d] bf16
  u16* vcb = (u16*)alloc((size_t)128 * 4096 * 2);  // [bh][d][nb(64)] bf16
  u16* locb = (u16*)alloc((size_t)8192 * 1024 * 2);
  u16* compb = (u16*)alloc((size_t)8192 * 1024 * 2);
  float* hraw = (float*)alloc((size_t)8192 * 4);
  float* gates = (float*)alloc(64);
  u16* combb = (u16*)alloc((size_t)8192 * 1024 * 2);

  fused_cast<<<12801, 256, 0, stream>>>(x, c_attn_w, c_proj_w, conv_w, xb, wab, wpb, wcb, kcb,
                                        vcb);

  gemm_bt<1><<<dim3(64, 24), 256, 0, stream>>>(xb, wab, qkvb, 8192, 3072, 1024);

  compress_kernel<<<dim3(252, 2), 256, 0, stream>>>(qkvb, wcb, ln_comp_w, kcb, vcb);

  attn_fused<<<dim3(128, 16), 256, 0, stream>>>(qkvb, kcb, vcb, locb, compb);

  gate_gemv<<<256, 256, 0, stream>>>(locb, compb, ln_local_w, gate_w1, hraw);
  gate_fin<<<8, 256, 0, stream>>>(hraw, gate_ln_w, gate_w2, gates);

  combine_ln_cast<<<8192, 256, 0, stream>>>(locb, compb, ln_local_w, gates, combb);

  gemm_bt<0><<<dim3(64, 8), 256, 0, stream>>>(combb, wpb, y, 8192, 1024, 1024);
}

// Round 7
// 272.672 us; speedup vs baseline: 1.0816x; 1.0347x over previous
//
#include <hip/hip_runtime.h>
#include <cstdint>
#include <cmath>
#include <cstddef>

typedef unsigned int u32;
typedef unsigned short u16;
typedef __bf16 bf16x8 __attribute__((ext_vector_type(8)));
typedef float f32x4 __attribute__((ext_vector_type(4)));
typedef u32 u32x4 __attribute__((ext_vector_type(4)));
typedef u32 u32x2 __attribute__((ext_vector_type(2)));

#define DEV static __device__ __forceinline__

// ---------- helpers ----------
DEV float bflo(u32 u) { return __uint_as_float(u << 16); }
DEV float bfhi(u32 u) { return __uint_as_float(u & 0xffff0000u); }
DEV u16 f2bf(float f) {               // RNE fp32 -> bf16
  u32 u = __float_as_uint(f);
  u += 0x7fffu + ((u >> 16) & 1u);
  return (u16)(u >> 16);
}
DEV f32x4 unpack_bf4(u32x2 r) {
  return (f32x4){bflo(r[0]), bfhi(r[0]), bflo(r[1]), bfhi(r[1])};
}
DEV float wredsum(float v) {
#pragma unroll
  for (int o = 32; o; o >>= 1) v += __shfl_xor(v, o, 64);
  return v;
}

// async global->LDS, 16B per lane. LDS dest is wave-uniform base + lane*16.
DEV void gload_lds16(const u16* g, u16* lds_base) {
  __builtin_amdgcn_global_load_lds((const __attribute__((address_space(1))) void*)g,
                                   (__attribute__((address_space(3))) void*)lds_base,
                                   16, 0, 0);
}

// ---------- fused casts + workspace pad zeroing ----------
__global__ __launch_bounds__(256) void fused_cast(const float* __restrict__ x,
                                                  const float* __restrict__ aw,
                                                  const float* __restrict__ pw,
                                                  const float* __restrict__ cw,
                                                  u16* __restrict__ xb,
                                                  u16* __restrict__ wab,
                                                  u16* __restrict__ wpb,
                                                  u16* __restrict__ wcb,
                                                  u16* __restrict__ kcb,
                                                  u16* __restrict__ vcb) {
  const int blk = blockIdx.x;
  if (blk < 12288) {
    const float* src;
    u16* dst;
    int base;
    if (blk < 8192) { src = x; dst = xb; base = blk; }
    else if (blk < 11264) { src = aw; dst = wab; base = blk - 8192; }
    else { src = pw; dst = wpb; base = blk - 11264; }
    const size_t idx = ((size_t)base * 256 + threadIdx.x) * 4;
    const f32x4 v = *(const f32x4*)&src[idx];
    u32x2 r;
    r[0] = (u32)f2bf(v[0]) | ((u32)f2bf(v[1]) << 16);
    r[1] = (u32)f2bf(v[2]) | ((u32)f2bf(v[3]) << 16);
    *(u32x2*)&dst[idx] = r;
  } else if (blk < 12800) {
    // conv_w [64][64][32] (o,i,kk) fp32 -> Wc[o][kk*64+i] bf16
    const int idx = (blk - 12288) * 256 + threadIdx.x;
    const int o = idx >> 11;
    const int rest = idx & 2047;
    const int i = rest >> 5;
    const int kk = rest & 31;
    wcb[(o << 11) + (kk << 6) + i] = f2bf(cw[idx]);
  } else {
    for (int i = threadIdx.x; i < 8192; i += 256) {
      const int bh = i >> 6, d = i & 63;
      kcb[bh * 4096 + 63 * 64 + d] = 0;   // K-block row 63 (pad)
      vcb[bh * 4096 + d * 64 + 63] = 0;   // V col 63 (pad)
    }
  }
}

// ---------- MFMA GEMM: out[M,N] = A[M,K](bf16) * B[N,K](bf16)^T ----------
// 128x128 tile, BK=64, 256 threads; global_load_lds width=16.
// XOR-swizzled LDS. At the m97-structure ceiling (~935 TF).
// NOTE (round-1): 8-phase port without full derived-waits regressed (567 TF).
// NOTE (round-4): XCD-chunk swizzle regressed 4.3x FETCH — keep 2-D grid.
template <int OUT_BF16>
__global__ __launch_bounds__(256, 4) void gemm_bt(const u16* __restrict__ A,
                                                  const u16* __restrict__ Bm,
                                                  void* __restrict__ out,
                                                  int M, int N, int K) {
  __shared__ u16 As[128 * 64];
  __shared__ u16 Bs[128 * 64];
  const int tid = threadIdx.x;
  const int lane = tid & 63;
  const int w = tid >> 6;
  const int row0 = blockIdx.x * 128;
  const int col0 = blockIdx.y * 128;
  const int wm = (w >> 1) * 64, wn = (w & 1) * 64;
  const int lr = lane & 15, lq = lane >> 4;
  const int srow = lane >> 3;
  const int scol = ((lane & 7) ^ (srow & 7)) * 8;
  const int pgA = ((lq ^ (lr & 7)) * 8);  // ks=0; ks=1 is pgA ^ 32

  f32x4 acc[4][4] = {};

  for (int k0 = 0; k0 < K; k0 += 64) {
    __syncthreads();
#pragma unroll
    for (int c = 0; c < 4; ++c) {
      const int base_r = w * 32 + c * 8;   // wave-uniform
      gload_lds16(&A[(size_t)(row0 + base_r + srow) * K + k0 + scol], &As[base_r * 64]);
      gload_lds16(&Bm[(size_t)(col0 + base_r + srow) * K + k0 + scol], &Bs[base_r * 64]);
    }
    __syncthreads();
#pragma unroll
    for (int ks = 0; ks < 2; ++ks) {
      const int pg = pgA ^ (ks << 5);
      bf16x8 af[4], bfr[4];
#pragma unroll
      for (int i = 0; i < 4; ++i) {
        af[i] = *(const bf16x8*)&As[(wm + i * 16 + lr) * 64 + pg];
        bfr[i] = *(const bf16x8*)&Bs[(wn + i * 16 + lr) * 64 + pg];
      }
#pragma unroll
      for (int i = 0; i < 4; ++i)
#pragma unroll
        for (int j = 0; j < 4; ++j)
          acc[i][j] = __builtin_amdgcn_mfma_f32_16x16x32_bf16(af[i], bfr[j], acc[i][j], 0, 0, 0);
    }
  }
#pragma unroll
  for (int i = 0; i < 4; ++i)
#pragma unroll
    for (int j = 0; j < 4; ++j)
#pragma unroll
      for (int rr = 0; rr < 4; ++rr) {
        const int gr = row0 + wm + i * 16 + lq * 4 + rr;
        const int gc = col0 + wn + j * 16 + lr;
        const float v = acc[i][j][rr];
        if (OUT_BF16)
          ((u16*)out)[(size_t)gr * N + gc] = f2bf(v);
        else
          ((float*)out)[(size_t)gr * N + gc] = v;
      }
}

// ---------- compression: conv(K=32,stride16) as GEMM + LN(64) + GELU ----------
// BM=32 tiles, grid (252, 2); BK=128 double-buffered (round-2 win).
__global__ __launch_bounds__(256) void compress_kernel(const u16* __restrict__ qkv,
                                                       const u16* __restrict__ Wc,
                                                       const float* __restrict__ ln_w,
                                                       u16* __restrict__ kcb,
                                                       u16* __restrict__ vcb) {
  __shared__ u16 As[2][32 * 128];   // 16 KB
  __shared__ u16 Bs[2][64 * 128];   // 32 KB
  __shared__ float Cs[32][65];      // 8.3 KB
  const int tid = threadIdx.x;
  const int lane = tid & 63, w = tid >> 6;
  const int lr = lane & 15, lq = lane >> 4;
  const int r0 = blockIdx.x * 32;
  const int srcoff = 1024 + (int)blockIdx.y * 1024;

  size_t abase[2];
#pragma unroll
  for (int g2 = 0; g2 < 2; ++g2) {
    const int r = 8 * w + 4 * g2 + (lane >> 4);       // 0..31
    const int gr = r0 + r;
    const int bh = gr / 63;
    const int nb = gr - bh * 63;
    const int b = bh >> 4, h = bh & 15;
    const int jbit = (lane >> 3) & 1;                 // L>>3
    const int icol = ((lane & 7) ^ (r & 7)) * 8;      // (L&7)*8
    abase[g2] = (size_t)(b * 1024 + nb * 16 + jbit) * 3072 + srcoff + h * 64 + icol;
  }
  size_t bbase[4];
#pragma unroll
  for (int c = 0; c < 4; ++c) {
    const int rB = 16 * w + 4 * c + (lane >> 4);      // 0..63
    const int Lcol = (((lane & 7) ^ (rB & 7)) | (lane & 8)) * 8;
    bbase[c] = (size_t)rB * 2048 + Lcol;
  }

  auto stage = [&](int it, int bs) {
#pragma unroll
    for (int g2 = 0; g2 < 2; ++g2)
      gload_lds16(&qkv[abase[g2] + (size_t)it * 6144], &As[bs][(8 * w + 4 * g2) * 128]);
#pragma unroll
    for (int c = 0; c < 4; ++c)
      gload_lds16(&Wc[bbase[c] + (size_t)it * 128], &Bs[bs][(16 * w + 4 * c) * 128]);
  };

  const int rw = (w & 1) * 16;   // row-half this wave computes
  const int cw = (w >> 1) * 32;  // col-half this wave computes
  f32x4 acc[2] = {};

  stage(0, 0);
  for (int it = 0; it < 16; ++it) {
    const int cur = it & 1;
    __syncthreads();               // drains stage for buf cur
    if (it < 15) stage(it + 1, cur ^ 1);
    const int rowA = rw + lr;
#pragma unroll
    for (int ks = 0; ks < 4; ++ks) {
      const int L = ks * 4 + lq;                       // logical 8-hw group 0..15
      const int pgA = (((L & 7) ^ (rowA & 7)) | (L & 8)) * 8;
      const bf16x8 af = *(const bf16x8*)&As[cur][rowA * 128 + pgA];
#pragma unroll
      for (int j = 0; j < 2; ++j) {
        const int rowB = cw + j * 16 + lr;
        const int pgB = (((L & 7) ^ (rowB & 7)) | (L & 8)) * 8;
        const bf16x8 bfr = *(const bf16x8*)&Bs[cur][rowB * 128 + pgB];
        acc[j] = __builtin_amdgcn_mfma_f32_16x16x32_bf16(af, bfr, acc[j], 0, 0, 0);
      }
    }
  }
  __syncthreads();
#pragma unroll
  for (int j = 0; j < 2; ++j)
#pragma unroll
    for (int rr = 0; rr < 4; ++rr)
      Cs[rw + lq * 4 + rr][cw + j * 16 + lr] = acc[j][rr];
  __syncthreads();
  if (tid < 32) {
    const int gr2 = r0 + tid;
    const int bh2 = gr2 / 63;
    const int nb2 = gr2 - bh2 * 63;
    float s = 0.f, s2 = 0.f;
#pragma unroll 8
    for (int d = 0; d < 64; ++d) {
      const float xv = Cs[tid][d];
      s += xv;
      s2 += xv * xv;
    }
    const float m = s * (1.f / 64.f);
    const float inv = rsqrtf(s2 * (1.f / 64.f) - m * m + 1e-5f);
    if (blockIdx.y == 0) {
      const size_t gb = (size_t)bh2 * 4096 + nb2 * 64;
#pragma unroll 8
      for (int d = 0; d < 64; ++d) {
        const float z = (Cs[tid][d] - m) * inv * ln_w[d];
        kcb[gb + d] = f2bf(0.5f * z * (1.f + erff(z * 0.70710678118f)));
      }
    } else {
      const size_t gb = (size_t)bh2 * 4096 + nb2;
#pragma unroll 8
      for (int d = 0; d < 64; ++d) {
        const float z = (Cs[tid][d] - m) * inv * ln_w[d];
        vcb[gb + d * 64] = f2bf(0.5f * z * (1.f + erff(z * 0.70710678118f)));
      }
    }
  }
}

// ---------- fused attention: local banded (window 129) + compressed-KV ----------
// grid (B*H, T/64); block 256 = 4 waves; wave w owns query rows w*16..w*16+15.
// Round-6: barrier chain 8 -> 4.
//  * Full swizzled Vt[64][200] written once pre-barrier-1 (region disjoint
//    from Ks) — removes the round-3 d-half ping-pong's 2 barriers and halves
//    the Ps pf re-reads.
//  * P->PV and Pc->PV need NO barrier: each wave writes/reads only its own 16
//    P rows (footprint audit: written tiles + zero tile exactly cover the
//    wave's 160-wide read window); same-wave DS ops are pipeline-ordered.
//    A compiler memory fence (asm "":::"memory") prevents reordering.
//  * Kept: Vt XOR swizzle by (row>>3) (round-3 conflict fix), T14 reg
//    prefetch of Kc/Vc.
__global__ __launch_bounds__(256, 4) void attn_fused(const u16* __restrict__ qkv,
                                                     const u16* __restrict__ kcb,
                                                     const u16* __restrict__ vcb,
                                                     u16* __restrict__ loc,
                                                     u16* __restrict__ outc) {
  __shared__ __align__(16) char smem[53248];
  u16* Ks = (u16*)smem;            // [192][72] bf16 (27648 B)
  u16* Ps = (u16*)smem;            // [64][200] bf16, overlays Ks after (2)
  u16* Vt = (u16*)(smem + 27648);  // [64][200] bf16, XOR-swizzled col groups
  u16* Kc = (u16*)smem;            // [64][72] compressed phase
  u16* Vc = (u16*)(smem + 9216);   // [64][72]
  u16* Pc = (u16*)(smem + 18432);  // [64][72]
  const int bh = blockIdx.x;
  const int b = bh >> 4, h = bh & 15;
  const int i0 = blockIdx.y * 64;
  const int jbase = i0 - 128;
  const int tid = threadIdx.x;
  const int lane = tid & 63, w = tid >> 6;
  const int lr = lane & 15, lq = lane >> 4;

  // stage K into Ks and V (transposed+swizzled) into Vt; Q fragments from global
#pragma unroll
  for (int c = 0; c < 6; ++c) {
    const int lin = c * 256 + tid;
    const int s = lin >> 3, d0 = (lin & 7) * 8;   // d0>>3 == lane&7
    const int j = jbase + s;
    u32x4 kval = {0, 0, 0, 0}, vval = {0, 0, 0, 0};
    if (j >= 0) {
      const size_t ro = (size_t)(b * 1024 + j) * 3072 + h * 64 + d0;
      kval = *(const u32x4*)&qkv[ro + 1024];
      vval = *(const u32x4*)&qkv[ro + 2048];
    }
    *(u32x4*)&Ks[s * 72 + d0] = kval;
    const int sg = (((s >> 3) ^ (lane & 7)) << 3) | (s & 7);
#pragma unroll
    for (int q = 0; q < 4; ++q) {
      Vt[(d0 + 2 * q) * 200 + sg] = (u16)(vval[q] & 0xffffu);
      Vt[(d0 + 2 * q + 1) * 200 + sg] = (u16)(vval[q] >> 16);
    }
  }
  bf16x8 qf[2];
  {
    const size_t qrow = (size_t)(b * 1024 + i0 + w * 16 + lr) * 3072 + h * 64;
#pragma unroll
    for (int ks = 0; ks < 2; ++ks) qf[ks] = *(const bf16x8*)&qkv[qrow + ks * 32 + lq * 8];
  }
  // T14: prefetch compressed K/V (L2-resident) for the compressed phase
  const size_t cb = (size_t)bh * 4096;
  u32x4 kcreg[2], vcreg[2];
#pragma unroll
  for (int c2 = 0; c2 < 2; ++c2) {
    const int i2 = c2 * 256 + tid;
    const size_t o2 = (size_t)(i2 >> 3) * 64 + (i2 & 7) * 8;
    kcreg[c2] = *(const u32x4*)&kcb[cb + o2];
    vcreg[c2] = *(const u32x4*)&vcb[cb + o2];
  }
  __syncthreads();  // (1) Ks + Vt visible

  // S = Q*K^T over the 9 band tiles jt = w..w+8
  f32x4 sa[9];
#pragma unroll
  for (int j9 = 0; j9 < 9; ++j9) sa[j9] = (f32x4){0.f, 0.f, 0.f, 0.f};
#pragma unroll
  for (int ks = 0; ks < 2; ++ks)
#pragma unroll
    for (int j9 = 0; j9 < 9; ++j9) {
      const int jt = w + j9;
      const bf16x8 kf = *(const bf16x8*)&Ks[(jt * 16 + lr) * 72 + ks * 32 + lq * 8];
      sa[j9] = __builtin_amdgcn_mfma_f32_16x16x32_bf16(qf[ks], kf, sa[j9], 0, 0, 0);
    }

  const float NINF = -__builtin_inff();
  float mx[4] = {NINF, NINF, NINF, NINF};
#pragma unroll
  for (int j9 = 0; j9 < 9; ++j9) {
    const int s = (w + j9) * 16 + lr;
#pragma unroll
    for (int rr = 0; rr < 4; ++rr) {
      const int qi = w * 16 + lq * 4 + rr;
      const bool valid = (jbase + s >= 0) && (s >= qi) && (s <= qi + 128);
      const float v = valid ? sa[j9][rr] * 0.125f : NINF;
      sa[j9][rr] = v;
      mx[rr] = fmaxf(mx[rr], v);
    }
  }
#pragma unroll
  for (int rr = 0; rr < 4; ++rr)
#pragma unroll
    for (int o = 1; o < 16; o <<= 1) mx[rr] = fmaxf(mx[rr], __shfl_xor(mx[rr], o, 64));
  float sum[4] = {0.f, 0.f, 0.f, 0.f};
#pragma unroll
  for (int j9 = 0; j9 < 9; ++j9)
#pragma unroll
    for (int rr = 0; rr < 4; ++rr) {
      const float p = __expf(sa[j9][rr] - mx[rr]);
      sa[j9][rr] = p;
      sum[rr] += p;
    }
#pragma unroll
  for (int rr = 0; rr < 4; ++rr) {
#pragma unroll
    for (int o = 1; o < 16; o <<= 1) sum[rr] += __shfl_xor(sum[rr], o, 64);
    sum[rr] = 1.0f / sum[rr];
  }
  __syncthreads();  // (2) all Ks reads done before Ps overlays

  // write P (own 9 tiles + 1 zero tile to cover the wave's 160-wide window)
#pragma unroll
  for (int j9 = 0; j9 < 9; ++j9) {
    const int jt = w + j9;
#pragma unroll
    for (int rr = 0; rr < 4; ++rr)
      Ps[(w * 16 + lq * 4 + rr) * 200 + jt * 16 + lr] = f2bf(sa[j9][rr] * sum[rr]);
  }
  {
    const int jz = (w == 0) ? 9 : (w == 1) ? 0 : (w == 2) ? 11 : 2;
#pragma unroll
    for (int rr = 0; rr < 4; ++rr) Ps[(w * 16 + lq * 4 + rr) * 200 + jz * 16 + lr] = 0;
  }
  // no barrier: pf reads only this wave's own Ps rows; fence stops compiler
  // reordering the (differently-typed) LDS reads above the writes.
  asm volatile("" ::: "memory");

  // O = P*V over the wave's 160-wide window (5 K-steps, swizzled Vt reads)
  const int W = (w >> 1) * 32;  // halfword offset of the window
  const int G0 = W >> 3;
  f32x4 oa[4];
#pragma unroll
  for (int jt = 0; jt < 4; ++jt) oa[jt] = (f32x4){0.f, 0.f, 0.f, 0.f};
#pragma unroll
  for (int ks = 0; ks < 5; ++ks) {
    const bf16x8 pf = *(const bf16x8*)&Ps[(w * 16 + lr) * 200 + W + ks * 32 + lq * 8];
#pragma unroll
    for (int jt = 0; jt < 4; ++jt) {
      const int rl = jt * 16 + lr;
      const int g = G0 + ks * 4 + lq;
      const bf16x8 vf = *(const bf16x8*)&Vt[rl * 200 + ((g ^ (rl >> 3)) << 3)];
      oa[jt] = __builtin_amdgcn_mfma_f32_16x16x32_bf16(pf, vf, oa[jt], 0, 0, 0);
    }
  }
#pragma unroll
  for (int jt = 0; jt < 4; ++jt)
#pragma unroll
    for (int rr = 0; rr < 4; ++rr)
      loc[(size_t)(b * 1024 + i0 + w * 16 + lq * 4 + rr) * 1024 + h * 64 + jt * 16 + lr] =
          f2bf(oa[jt][rr]);

  // ===== compressed-KV phase (reuses qf; Kc/Vc/Pc overlay Ks/Ps region) =====
  __syncthreads();  // (3) all Ps reads done before overlay
#pragma unroll
  for (int c2 = 0; c2 < 2; ++c2) {
    const int i2 = c2 * 256 + tid;
    const int r2 = i2 >> 3, o2 = (i2 & 7) * 8;
    *(u32x4*)&Kc[r2 * 72 + o2] = kcreg[c2];
    *(u32x4*)&Vc[r2 * 72 + o2] = vcreg[c2];
  }
  __syncthreads();  // (4) Kc/Vc visible

  f32x4 ca[4];
#pragma unroll
  for (int j = 0; j < 4; ++j) ca[j] = (f32x4){0.f, 0.f, 0.f, 0.f};
#pragma unroll
  for (int ks = 0; ks < 2; ++ks)
#pragma unroll
    for (int j = 0; j < 4; ++j) {
      const bf16x8 kf = *(const bf16x8*)&Kc[(j * 16 + lr) * 72 + ks * 32 + lq * 8];
      ca[j] = __builtin_amdgcn_mfma_f32_16x16x32_bf16(qf[ks], kf, ca[j], 0, 0, 0);
    }
  float mc[4] = {NINF, NINF, NINF, NINF};
#pragma unroll
  for (int j = 0; j < 4; ++j) {
    const int s = j * 16 + lr;
#pragma unroll
    for (int rr = 0; rr < 4; ++rr) {
      const int i = i0 + w * 16 + lq * 4 + rr;
      const bool valid = (s <= i) && (s < 63);
      const float v = valid ? ca[j][rr] * 0.125f : NINF;
      ca[j][rr] = v;
      mc[rr] = fmaxf(mc[rr], v);
    }
  }
#pragma unroll
  for (int rr = 0; rr < 4; ++rr)
#pragma unroll
    for (int o = 1; o < 16; o <<= 1) mc[rr] = fmaxf(mc[rr], __shfl_xor(mc[rr], o, 64));
  float sc[4] = {0.f, 0.f, 0.f, 0.f};
#pragma unroll
  for (int j = 0; j < 4; ++j)
#pragma unroll
    for (int rr = 0; rr < 4; ++rr) {
      const float p = __expf(ca[j][rr] - mc[rr]);
      ca[j][rr] = p;
      sc[rr] += p;
    }
#pragma unroll
  for (int rr = 0; rr < 4; ++rr) {
#pragma unroll
    for (int o = 1; o < 16; o <<= 1) sc[rr] += __shfl_xor(sc[rr], o, 64);
    sc[rr] = 1.0f / sc[rr];
  }
#pragma unroll
  for (int j = 0; j < 4; ++j)
#pragma unroll
    for (int rr = 0; rr < 4; ++rr)
      Pc[(w * 16 + lq * 4 + rr) * 72 + j * 16 + lr] = f2bf(ca[j][rr] * sc[rr]);
  // no barrier: pf reads only this wave's own Pc rows; Pc region is disjoint
  // from Kc/Vc so no cross-wave WAR either.
  asm volatile("" ::: "memory");

  f32x4 co[4];
#pragma unroll
  for (int jt = 0; jt < 4; ++jt) co[jt] = (f32x4){0.f, 0.f, 0.f, 0.f};
#pragma unroll
  for (int ks = 0; ks < 2; ++ks) {
    const bf16x8 pf = *(const bf16x8*)&Pc[(w * 16 + lr) * 72 + ks * 32 + lq * 8];
#pragma unroll
    for (int jt = 0; jt < 4; ++jt) {
      const bf16x8 vf = *(const bf16x8*)&Vc[(jt * 16 + lr) * 72 + ks * 32 + lq * 8];
      co[jt] = __builtin_amdgcn_mfma_f32_16x16x32_bf16(pf, vf, co[jt], 0, 0, 0);
    }
  }
#pragma unroll
  for (int jt = 0; jt < 4; ++jt)
#pragma unroll
    for (int rr = 0; rr < 4; ++rr)
      outc[(size_t)(b * 1024 + i0 + w * 16 + lq * 4 + rr) * 1024 + h * 64 + jt * 16 + lr] =
          f2bf(co[jt][rr]);
}

// ---------- gating GEMV (LN of local last rows folded in, round-4) ----------
__global__ __launch_bounds__(256) void gate_gemv(const u16* __restrict__ locb,
                                                 const u16* __restrict__ compb,
                                                 const float* __restrict__ lnw,
                                                 const float* __restrict__ w1,
                                                 float* __restrict__ hraw) {
  __shared__ float sm[8], sinv[8];
  const int tid = threadIdx.x;
  const int w = tid >> 6, lane = tid & 63;
  for (int bb = w; bb < 8; bb += 4) {
    const u16* rp = &locb[((size_t)bb * 1024 + 1023) * 1024 + lane * 16];
    const u32x4 a0 = *(const u32x4*)rp;
    const u32x4 a1 = *(const u32x4*)(rp + 8);
    float s = 0.f, s2 = 0.f;
#pragma unroll
    for (int q = 0; q < 4; ++q) {
      const float x0 = bflo(a0[q]), x1 = bfhi(a0[q]);
      const float x2 = bflo(a1[q]), x3 = bfhi(a1[q]);
      s += x0 + x1 + x2 + x3;
      s2 += x0 * x0 + x1 * x1 + x2 * x2 + x3 * x3;
    }
    s = wredsum(s);
    s2 = wredsum(s2);
    if (!lane) {
      const float m = s * (1.f / 1024.f);
      sm[bb] = m;
      sinv[bb] = rsqrtf(s2 * (1.f / 1024.f) - m * m + 1e-5f);
    }
  }
  __syncthreads();

  const int o = blockIdx.x * 4 + w;
  const float* wr = &w1[(size_t)o * 2048];
  float acc[8] = {};
#pragma unroll
  for (int it = 0; it < 4; ++it) {     // c in [0,1024): LN(local) on the fly
    const int c = (it * 64 + lane) * 4;
    const f32x4 wv = *(const f32x4*)&wr[c];
    const f32x4 lw = *(const f32x4*)&lnw[c];
#pragma unroll
    for (int b = 0; b < 8; ++b) {
      const f32x4 xv = unpack_bf4(*(const u32x2*)&locb[((size_t)b * 1024 + 1023) * 1024 + c]);
      const float mb = sm[b], ib = sinv[b];
      acc[b] += ((xv[0] - mb) * ib * lw[0]) * wv[0] + ((xv[1] - mb) * ib * lw[1]) * wv[1] +
                ((xv[2] - mb) * ib * lw[2]) * wv[2] + ((xv[3] - mb) * ib * lw[3]) * wv[3];
    }
  }
#pragma unroll
  for (int it = 4; it < 8; ++it) {     // c in [1024,2048): comp raw
    const int c = (it * 64 + lane) * 4;
    const f32x4 wv = *(const f32x4*)&wr[c];
    const int c2 = c - 1024;
#pragma unroll
    for (int b = 0; b < 8; ++b) {
      const f32x4 fv = unpack_bf4(*(const u32x2*)&compb[((size_t)b * 1024 + 1023) * 1024 + c2]);
      acc[b] += fv[0] * wv[0] + fv[1] * wv[1] + fv[2] * wv[2] + fv[3] * wv[3];
    }
  }
#pragma unroll
  for (int b = 0; b < 8; ++b) acc[b] = wredsum(acc[b]);
  if (lane == 0) {
#pragma unroll
    for (int b = 0; b < 8; ++b) hraw[b * 1024 + o] = acc[b];
  }
}

// ---------- gating finalize: LN + ReLU + 2-way GEMV + softmax ----------
__global__ __launch_bounds__(256) void gate_fin(const float* __restrict__ hraw,
                                                const float* __restrict__ lnw,
                                                const float* __restrict__ w2,
                                                float* __restrict__ gates) {
  const int b = blockIdx.x, tid = threadIdx.x;
  const f32x4 v = *(const f32x4*)&hraw[(size_t)b * 1024 + tid * 4];
  float s = v[0] + v[1] + v[2] + v[3];
  float s2 = v[0] * v[0] + v[1] * v[1] + v[2] * v[2] + v[3] * v[3];
  s = wredsum(s);
  s2 = wredsum(s2);
  __shared__ float rs[4], rs2[4];
  const int w = tid >> 6, lane = tid & 63;
  if (!lane) { rs[w] = s; rs2[w] = s2; }
  __syncthreads();
  s = rs[0] + rs[1] + rs[2] + rs[3];
  s2 = rs2[0] + rs2[1] + rs2[2] + rs2[3];
  const float m = s * (1.f / 1024.f);
  const float inv = rsqrtf(s2 * (1.f / 1024.f) - m * m + 1e-5f);
  float p0 = 0.f, p1 = 0.f;
#pragma unroll
  for (int k = 0; k < 4; ++k) {
    float hh = (v[k] - m) * inv * lnw[tid * 4 + k];
    hh = fmaxf(hh, 0.f);
    p0 += hh * w2[tid * 4 + k];
    p1 += hh * w2[1024 + tid * 4 + k];
  }
  p0 = wredsum(p0);
  p1 = wredsum(p1);
  __syncthreads();
  if (!lane) { rs[w] = p0; rs2[w] = p1; }
  __syncthreads();
  if (tid == 0) {
    const float l0 = rs[0] + rs[1] + rs[2] + rs[3];
    const float l1 = rs2[0] + rs2[1] + rs2[2] + rs2[3];
    const float mm = fmaxf(l0, l1);
    const float e0 = __expf(l0 - mm), e1 = __expf(l1 - mm);
    const float iv = 1.f / (e0 + e1);
    gates[b * 2] = e0 * iv;
    gates[b * 2 + 1] = e1 * iv;
  }
}

// ---------- fused: per-row LN of local_out + gate-combine + bf16 cast ----------
// Round-6: wave-per-row (4 rows/block), no block barriers, 16B loads/stores.
__global__ __launch_bounds__(256) void combine_ln_cast(const u16* __restrict__ locb,
                                                       const u16* __restrict__ compb,
                                                       const float* __restrict__ lnw,
                                                       const float* __restrict__ gates,
                                                       u16* __restrict__ outb) {
  const int w = threadIdx.x >> 6, lane = threadIdx.x & 63;
  const int row = blockIdx.x * 4 + w;
  const size_t base = (size_t)row * 1024 + lane * 16;
  const u32x4 a0 = *(const u32x4*)&locb[base];
  const u32x4 a1 = *(const u32x4*)&locb[base + 8];
  float xv[16];
#pragma unroll
  for (int q = 0; q < 4; ++q) {
    xv[2 * q] = bflo(a0[q]);
    xv[2 * q + 1] = bfhi(a0[q]);
    xv[8 + 2 * q] = bflo(a1[q]);
    xv[8 + 2 * q + 1] = bfhi(a1[q]);
  }
  float s = 0.f, s2 = 0.f;
#pragma unroll
  for (int k = 0; k < 16; ++k) {
    s += xv[k];
    s2 += xv[k] * xv[k];
  }
  s = wredsum(s);
  s2 = wredsum(s2);
  const float m = s * (1.f / 1024.f);
  const float inv = rsqrtf(s2 * (1.f / 1024.f) - m * m + 1e-5f);
  const int b = row >> 10;
  const float g0 = gates[2 * b], g1 = gates[2 * b + 1];
  const u32x4 c0 = *(const u32x4*)&compb[base];
  const u32x4 c1 = *(const u32x4*)&compb[base + 8];
  const f32x4 lw0 = *(const f32x4*)&lnw[lane * 16];
  const f32x4 lw1 = *(const f32x4*)&lnw[lane * 16 + 4];
  const f32x4 lw2 = *(const f32x4*)&lnw[lane * 16 + 8];
  const f32x4 lw3 = *(const f32x4*)&lnw[lane * 16 + 12];
  u32x4 r0, r1;
#pragma unroll
  for (int q = 0; q < 4; ++q) {
    const float lwa = (q < 2) ? lw0[2 * q] : lw1[2 * q - 4];
    const float lwb = (q < 2) ? lw0[2 * q + 1] : lw1[2 * q - 3];
    const float lwc = (q < 2) ? lw2[2 * q] : lw3[2 * q - 4];
    const float lwd = (q < 2) ? lw2[2 * q + 1] : lw3[2 * q - 3];
    const float o0 = g0 * ((xv[2 * q] - m) * inv * lwa) + g1 * bflo(c0[q]);
    const float o1 = g0 * ((xv[2 * q + 1] - m) * inv * lwb) + g1 * bfhi(c0[q]);
    const float o2 = g0 * ((xv[8 + 2 * q] - m) * inv * lwc) + g1 * bflo(c1[q]);
    const float o3 = g0 * ((xv[8 + 2 * q + 1] - m) * inv * lwd) + g1 * bfhi(c1[q]);
    r0[q] = (u32)f2bf(o0) | ((u32)f2bf(o1) << 16);
    r1[q] = (u32)f2bf(o2) | ((u32)f2bf(o3) << 16);
  }
  *(u32x4*)&outb[base] = r0;
  *(u32x4*)&outb[base + 8] = r1;
}

// ---------- launcher ----------
extern "C" void kernel_launch(void* const* d_in, const int* in_sizes, int n_in,
                              void* d_out, int out_size, void* d_ws, size_t ws_size,
                              hipStream_t stream) {
  const float* x = (const float*)d_in[0];
  const float* c_attn_w = (const float*)d_in[1];
  const float* conv_w = (const float*)d_in[2];
  const float* ln_comp_w = (const float*)d_in[3];
  const float* ln_local_w = (const float*)d_in[4];
  const float* gate_w1 = (const float*)d_in[5];
  const float* gate_ln_w = (const float*)d_in[6];
  const float* gate_w2 = (const float*)d_in[7];
  const float* c_proj_w = (const float*)d_in[8];
  float* y = (float*)d_out;

  char* ws = (char*)d_ws;
  size_t off = 0;
  auto alloc = [&](size_t bytes) -> void* {
    void* p = ws + off;
    off += (bytes + 255) & ~(size_t)255;
    return p;
  };
  u16* qkvb = (u16*)alloc((size_t)8192 * 3072 * 2);
  u16* xb = (u16*)alloc((size_t)8192 * 1024 * 2);
  u16* wab = (u16*)alloc((size_t)3072 * 1024 * 2);
  u16* wpb = (u16*)alloc((size_t)1024 * 1024 * 2);
  u16* wcb = (u16*)alloc((size_t)64 * 2048 * 2);
  u16* kcb = (u16*)alloc((size_t)128 * 4096 * 2);  // [bh][nb(64)][d] bf16
  u16* vcb = (u16*)alloc((size_t)128 * 4096 * 2);  // [bh][d][nb(64)] bf16
  u16* locb = (u16*)alloc((size_t)8192 * 1024 * 2);
  u16* compb = (u16*)alloc((size_t)8192 * 1024 * 2);
  float* hraw = (float*)alloc((size_t)8192 * 4);
  float* gates = (float*)alloc(64);
  u16* combb = (u16*)alloc((size_t)8192 * 1024 * 2);

  fused_cast<<<12801, 256, 0, stream>>>(x, c_attn_w, c_proj_w, conv_w, xb, wab, wpb, wcb, kcb,
                                        vcb);

  gemm_bt<1><<<dim3(64, 24), 256, 0, stream>>>(xb, wab, qkvb, 8192, 3072, 1024);

  compress_kernel<<<dim3(252, 2), 256, 0, stream>>>(qkvb, wcb, ln_comp_w, kcb, vcb);

  attn_fused<<<dim3(128, 16), 256, 0, stream>>>(qkvb, kcb, vcb, locb, compb);

  gate_gemv<<<256, 256, 0, stream>>>(locb, compb, ln_local_w, gate_w1, hraw);
  gate_fin<<<8, 256, 0, stream>>>(hraw, gate_ln_w, gate_w2, gates);

  combine_ln_cast<<<2048, 256, 0, stream>>>(locb, compb, ln_local_w, gates, combb);

  gemm_bt<0><<<dim3(64, 8), 256, 0, stream>>>(combb, wpb, y, 8192, 1024, 1024);
}

// Round 8
// 260.920 us; speedup vs baseline: 1.1303x; 1.0450x over previous
//
#include <hip/hip_runtime.h>
#include <cstdint>
#include <cmath>
#include <cstddef>

typedef unsigned int u32;
typedef unsigned short u16;
typedef __bf16 bf16x8 __attribute__((ext_vector_type(8)));
typedef float f32x4 __attribute__((ext_vector_type(4)));
typedef u32 u32x4 __attribute__((ext_vector_type(4)));
typedef u32 u32x2 __attribute__((ext_vector_type(2)));

#define DEV static __device__ __forceinline__

// ---------- helpers ----------
DEV float bflo(u32 u) { return __uint_as_float(u << 16); }
DEV float bfhi(u32 u) { return __uint_as_float(u & 0xffff0000u); }
DEV u16 f2bf(float f) {               // RNE fp32 -> bf16
  u32 u = __float_as_uint(f);
  u += 0x7fffu + ((u >> 16) & 1u);
  return (u16)(u >> 16);
}
DEV f32x4 unpack_bf4(u32x2 r) {
  return (f32x4){bflo(r[0]), bfhi(r[0]), bflo(r[1]), bfhi(r[1])};
}
DEV float wredsum(float v) {
#pragma unroll
  for (int o = 32; o; o >>= 1) v += __shfl_xor(v, o, 64);
  return v;
}

// async global->LDS, 16B per lane. LDS dest is wave-uniform base + lane*16.
DEV void gload_lds16(const u16* g, u16* lds_base) {
  __builtin_amdgcn_global_load_lds((const __attribute__((address_space(1))) void*)g,
                                   (__attribute__((address_space(3))) void*)lds_base,
                                   16, 0, 0);
}

// ---------- fused casts + workspace pad zeroing ----------
__global__ __launch_bounds__(256) void fused_cast(const float* __restrict__ x,
                                                  const float* __restrict__ aw,
                                                  const float* __restrict__ pw,
                                                  const float* __restrict__ cw,
                                                  u16* __restrict__ xb,
                                                  u16* __restrict__ wab,
                                                  u16* __restrict__ wpb,
                                                  u16* __restrict__ wcb,
                                                  u16* __restrict__ kcb,
                                                  u16* __restrict__ vcb) {
  const int blk = blockIdx.x;
  if (blk < 12288) {
    const float* src;
    u16* dst;
    int base;
    if (blk < 8192) { src = x; dst = xb; base = blk; }
    else if (blk < 11264) { src = aw; dst = wab; base = blk - 8192; }
    else { src = pw; dst = wpb; base = blk - 11264; }
    const size_t idx = ((size_t)base * 256 + threadIdx.x) * 4;
    const f32x4 v = *(const f32x4*)&src[idx];
    u32x2 r;
    r[0] = (u32)f2bf(v[0]) | ((u32)f2bf(v[1]) << 16);
    r[1] = (u32)f2bf(v[2]) | ((u32)f2bf(v[3]) << 16);
    *(u32x2*)&dst[idx] = r;
  } else if (blk < 12800) {
    // conv_w [64][64][32] (o,i,kk) fp32 -> Wc[o][kk*64+i] bf16
    const int idx = (blk - 12288) * 256 + threadIdx.x;
    const int o = idx >> 11;
    const int rest = idx & 2047;
    const int i = rest >> 5;
    const int kk = rest & 31;
    wcb[(o << 11) + (kk << 6) + i] = f2bf(cw[idx]);
  } else {
    for (int i = threadIdx.x; i < 8192; i += 256) {
      const int bh = i >> 6, d = i & 63;
      kcb[bh * 4096 + 63 * 64 + d] = 0;   // K-block row 63 (pad)
      vcb[bh * 4096 + d * 64 + 63] = 0;   // V col 63 (pad)
    }
  }
}

// ---------- MFMA GEMM: out[M,N] = A[M,K](bf16) * B[N,K](bf16)^T ----------
// 128x128 tile, BK=64, 256 threads; global_load_lds width=16.
// XOR-swizzled LDS. At the m97-structure ceiling (~935 TF).
// NOTE (round-1): 8-phase port without full derived-waits regressed (567 TF).
// NOTE (round-4): XCD-chunk swizzle regressed 4.3x FETCH — keep 2-D grid.
template <int OUT_BF16>
__global__ __launch_bounds__(256, 4) void gemm_bt(const u16* __restrict__ A,
                                                  const u16* __restrict__ Bm,
                                                  void* __restrict__ out,
                                                  int M, int N, int K) {
  __shared__ u16 As[128 * 64];
  __shared__ u16 Bs[128 * 64];
  const int tid = threadIdx.x;
  const int lane = tid & 63;
  const int w = tid >> 6;
  const int row0 = blockIdx.x * 128;
  const int col0 = blockIdx.y * 128;
  const int wm = (w >> 1) * 64, wn = (w & 1) * 64;
  const int lr = lane & 15, lq = lane >> 4;
  const int srow = lane >> 3;
  const int scol = ((lane & 7) ^ (srow & 7)) * 8;
  const int pgA = ((lq ^ (lr & 7)) * 8);  // ks=0; ks=1 is pgA ^ 32

  f32x4 acc[4][4] = {};

  for (int k0 = 0; k0 < K; k0 += 64) {
    __syncthreads();
#pragma unroll
    for (int c = 0; c < 4; ++c) {
      const int base_r = w * 32 + c * 8;   // wave-uniform
      gload_lds16(&A[(size_t)(row0 + base_r + srow) * K + k0 + scol], &As[base_r * 64]);
      gload_lds16(&Bm[(size_t)(col0 + base_r + srow) * K + k0 + scol], &Bs[base_r * 64]);
    }
    __syncthreads();
#pragma unroll
    for (int ks = 0; ks < 2; ++ks) {
      const int pg = pgA ^ (ks << 5);
      bf16x8 af[4], bfr[4];
#pragma unroll
      for (int i = 0; i < 4; ++i) {
        af[i] = *(const bf16x8*)&As[(wm + i * 16 + lr) * 64 + pg];
        bfr[i] = *(const bf16x8*)&Bs[(wn + i * 16 + lr) * 64 + pg];
      }
#pragma unroll
      for (int i = 0; i < 4; ++i)
#pragma unroll
        for (int j = 0; j < 4; ++j)
          acc[i][j] = __builtin_amdgcn_mfma_f32_16x16x32_bf16(af[i], bfr[j], acc[i][j], 0, 0, 0);
    }
  }
#pragma unroll
  for (int i = 0; i < 4; ++i)
#pragma unroll
    for (int j = 0; j < 4; ++j)
#pragma unroll
      for (int rr = 0; rr < 4; ++rr) {
        const int gr = row0 + wm + i * 16 + lq * 4 + rr;
        const int gc = col0 + wn + j * 16 + lr;
        const float v = acc[i][j][rr];
        if (OUT_BF16)
          ((u16*)out)[(size_t)gr * N + gc] = f2bf(v);
        else
          ((float*)out)[(size_t)gr * N + gc] = v;
      }
}

// ---------- compression: conv(K=32,stride16) as GEMM + LN(64) + GELU ----------
// BM=32 tiles, grid (252, 2); BK=128 double-buffered (round-2 win).
__global__ __launch_bounds__(256) void compress_kernel(const u16* __restrict__ qkv,
                                                       const u16* __restrict__ Wc,
                                                       const float* __restrict__ ln_w,
                                                       u16* __restrict__ kcb,
                                                       u16* __restrict__ vcb) {
  __shared__ u16 As[2][32 * 128];   // 16 KB
  __shared__ u16 Bs[2][64 * 128];   // 32 KB
  __shared__ float Cs[32][65];      // 8.3 KB
  const int tid = threadIdx.x;
  const int lane = tid & 63, w = tid >> 6;
  const int lr = lane & 15, lq = lane >> 4;
  const int r0 = blockIdx.x * 32;
  const int srcoff = 1024 + (int)blockIdx.y * 1024;

  size_t abase[2];
#pragma unroll
  for (int g2 = 0; g2 < 2; ++g2) {
    const int r = 8 * w + 4 * g2 + (lane >> 4);       // 0..31
    const int gr = r0 + r;
    const int bh = gr / 63;
    const int nb = gr - bh * 63;
    const int b = bh >> 4, h = bh & 15;
    const int jbit = (lane >> 3) & 1;                 // L>>3
    const int icol = ((lane & 7) ^ (r & 7)) * 8;      // (L&7)*8
    abase[g2] = (size_t)(b * 1024 + nb * 16 + jbit) * 3072 + srcoff + h * 64 + icol;
  }
  size_t bbase[4];
#pragma unroll
  for (int c = 0; c < 4; ++c) {
    const int rB = 16 * w + 4 * c + (lane >> 4);      // 0..63
    const int Lcol = (((lane & 7) ^ (rB & 7)) | (lane & 8)) * 8;
    bbase[c] = (size_t)rB * 2048 + Lcol;
  }

  auto stage = [&](int it, int bs) {
#pragma unroll
    for (int g2 = 0; g2 < 2; ++g2)
      gload_lds16(&qkv[abase[g2] + (size_t)it * 6144], &As[bs][(8 * w + 4 * g2) * 128]);
#pragma unroll
    for (int c = 0; c < 4; ++c)
      gload_lds16(&Wc[bbase[c] + (size_t)it * 128], &Bs[bs][(16 * w + 4 * c) * 128]);
  };

  const int rw = (w & 1) * 16;   // row-half this wave computes
  const int cw = (w >> 1) * 32;  // col-half this wave computes
  f32x4 acc[2] = {};

  stage(0, 0);
  for (int it = 0; it < 16; ++it) {
    const int cur = it & 1;
    __syncthreads();               // drains stage for buf cur
    if (it < 15) stage(it + 1, cur ^ 1);
    const int rowA = rw + lr;
#pragma unroll
    for (int ks = 0; ks < 4; ++ks) {
      const int L = ks * 4 + lq;                       // logical 8-hw group 0..15
      const int pgA = (((L & 7) ^ (rowA & 7)) | (L & 8)) * 8;
      const bf16x8 af = *(const bf16x8*)&As[cur][rowA * 128 + pgA];
#pragma unroll
      for (int j = 0; j < 2; ++j) {
        const int rowB = cw + j * 16 + lr;
        const int pgB = (((L & 7) ^ (rowB & 7)) | (L & 8)) * 8;
        const bf16x8 bfr = *(const bf16x8*)&Bs[cur][rowB * 128 + pgB];
        acc[j] = __builtin_amdgcn_mfma_f32_16x16x32_bf16(af, bfr, acc[j], 0, 0, 0);
      }
    }
  }
  __syncthreads();
#pragma unroll
  for (int j = 0; j < 2; ++j)
#pragma unroll
    for (int rr = 0; rr < 4; ++rr)
      Cs[rw + lq * 4 + rr][cw + j * 16 + lr] = acc[j][rr];
  __syncthreads();
  if (tid < 32) {
    const int gr2 = r0 + tid;
    const int bh2 = gr2 / 63;
    const int nb2 = gr2 - bh2 * 63;
    float s = 0.f, s2 = 0.f;
#pragma unroll 8
    for (int d = 0; d < 64; ++d) {
      const float xv = Cs[tid][d];
      s += xv;
      s2 += xv * xv;
    }
    const float m = s * (1.f / 64.f);
    const float inv = rsqrtf(s2 * (1.f / 64.f) - m * m + 1e-5f);
    if (blockIdx.y == 0) {
      const size_t gb = (size_t)bh2 * 4096 + nb2 * 64;
#pragma unroll 8
      for (int d = 0; d < 64; ++d) {
        const float z = (Cs[tid][d] - m) * inv * ln_w[d];
        kcb[gb + d] = f2bf(0.5f * z * (1.f + erff(z * 0.70710678118f)));
      }
    } else {
      const size_t gb = (size_t)bh2 * 4096 + nb2;
#pragma unroll 8
      for (int d = 0; d < 64; ++d) {
        const float z = (Cs[tid][d] - m) * inv * ln_w[d];
        vcb[gb + d * 64] = f2bf(0.5f * z * (1.f + erff(z * 0.70710678118f)));
      }
    }
  }
}

// ---------- fused attention: local banded (window 129) + compressed-KV ----------
// grid (B*H, T/64); block 256 = 4 waves; wave w owns query rows w*16..w*16+15.
// Round-6: 4-barrier chain (fence-only P->PV). Round-8: K staging via
// global_load_lds into a linear XOR-swizzled Ks[192][64] (gemm_bt pattern,
// 0-conflict verified) — removes the reg round-trip from the block-start
// critical path. Negative-j rows clamp to row 0; values discarded by the
// band mask (finite, no NaN risk).
__global__ __launch_bounds__(256, 4) void attn_fused(const u16* __restrict__ qkv,
                                                     const u16* __restrict__ kcb,
                                                     const u16* __restrict__ vcb,
                                                     u16* __restrict__ loc,
                                                     u16* __restrict__ outc) {
  __shared__ __align__(16) char smem[51200];
  u16* Ks = (u16*)smem;            // [192][64] bf16, swizzled (24576 B)
  u16* Ps = (u16*)smem;            // [64][200] bf16, overlays Ks after (2)
  u16* Vt = (u16*)(smem + 25600);  // [64][200] bf16, XOR-swizzled col groups
  u16* Kc = (u16*)smem;            // [64][72] compressed phase
  u16* Vc = (u16*)(smem + 9216);   // [64][72]
  u16* Pc = (u16*)(smem + 18432);  // [64][72]
  const int bh = blockIdx.x;
  const int b = bh >> 4, h = bh & 15;
  const int i0 = blockIdx.y * 64;
  const int jbase = i0 - 128;
  const int tid = threadIdx.x;
  const int lane = tid & 63, w = tid >> 6;
  const int lr = lane & 15, lq = lane >> 4;
  const int srow = lane >> 3;                 // 0..7
  const int scol = ((lane & 7) ^ srow) * 8;   // pre-swizzled source col group

  // stage K via async gload (swizzled linear Ks), issue first so loads fly
  // under the V reg path below
#pragma unroll
  for (int g = 0; g < 6; ++g) {
    const int rb = (w * 6 + g) * 8;           // wave-uniform, multiple of 8
    int jc = jbase + rb + srow;
    jc = jc < 0 ? 0 : jc;
    gload_lds16(&qkv[(size_t)(b * 1024 + jc) * 3072 + 1024 + h * 64 + scol], &Ks[rb * 64]);
  }
  // V: reg load + transposed swizzled write into Vt (disjoint from Ks)
#pragma unroll
  for (int c = 0; c < 6; ++c) {
    const int lin = c * 256 + tid;
    const int s = lin >> 3, d0 = (lin & 7) * 8;
    const int j = jbase + s;
    u32x4 vval = {0, 0, 0, 0};
    if (j >= 0) vval = *(const u32x4*)&qkv[(size_t)(b * 1024 + j) * 3072 + 2048 + h * 64 + d0];
    const int sg = (((s >> 3) ^ (lane & 7)) << 3) | (s & 7);
#pragma unroll
    for (int q = 0; q < 4; ++q) {
      Vt[(d0 + 2 * q) * 200 + sg] = (u16)(vval[q] & 0xffffu);
      Vt[(d0 + 2 * q + 1) * 200 + sg] = (u16)(vval[q] >> 16);
    }
  }
  bf16x8 qf[2];
  {
    const size_t qrow = (size_t)(b * 1024 + i0 + w * 16 + lr) * 3072 + h * 64;
#pragma unroll
    for (int ks = 0; ks < 2; ++ks) qf[ks] = *(const bf16x8*)&qkv[qrow + ks * 32 + lq * 8];
  }
  // T14: prefetch compressed K/V (L2-resident) for the compressed phase
  const size_t cb = (size_t)bh * 4096;
  u32x4 kcreg[2], vcreg[2];
#pragma unroll
  for (int c2 = 0; c2 < 2; ++c2) {
    const int i2 = c2 * 256 + tid;
    const size_t o2 = (size_t)(i2 >> 3) * 64 + (i2 & 7) * 8;
    kcreg[c2] = *(const u32x4*)&kcb[cb + o2];
    vcreg[c2] = *(const u32x4*)&vcb[cb + o2];
  }
  __syncthreads();  // (1) Ks + Vt visible (drains gload queue + ds writes)

  // S = Q*K^T over the 9 band tiles jt = w..w+8 (swizzled Ks reads)
  f32x4 sa[9];
#pragma unroll
  for (int j9 = 0; j9 < 9; ++j9) sa[j9] = (f32x4){0.f, 0.f, 0.f, 0.f};
#pragma unroll
  for (int ks = 0; ks < 2; ++ks)
#pragma unroll
    for (int j9 = 0; j9 < 9; ++j9) {
      const int jt = w + j9;
      const bf16x8 kf =
          *(const bf16x8*)&Ks[(jt * 16 + lr) * 64 + (((ks * 4 + lq) ^ (lr & 7)) * 8)];
      sa[j9] = __builtin_amdgcn_mfma_f32_16x16x32_bf16(qf[ks], kf, sa[j9], 0, 0, 0);
    }

  const float NINF = -__builtin_inff();
  float mx[4] = {NINF, NINF, NINF, NINF};
#pragma unroll
  for (int j9 = 0; j9 < 9; ++j9) {
    const int s = (w + j9) * 16 + lr;
#pragma unroll
    for (int rr = 0; rr < 4; ++rr) {
      const int qi = w * 16 + lq * 4 + rr;
      const bool valid = (jbase + s >= 0) && (s >= qi) && (s <= qi + 128);
      const float v = valid ? sa[j9][rr] * 0.125f : NINF;
      sa[j9][rr] = v;
      mx[rr] = fmaxf(mx[rr], v);
    }
  }
#pragma unroll
  for (int rr = 0; rr < 4; ++rr)
#pragma unroll
    for (int o = 1; o < 16; o <<= 1) mx[rr] = fmaxf(mx[rr], __shfl_xor(mx[rr], o, 64));
  float sum[4] = {0.f, 0.f, 0.f, 0.f};
#pragma unroll
  for (int j9 = 0; j9 < 9; ++j9)
#pragma unroll
    for (int rr = 0; rr < 4; ++rr) {
      const float p = __expf(sa[j9][rr] - mx[rr]);
      sa[j9][rr] = p;
      sum[rr] += p;
    }
#pragma unroll
  for (int rr = 0; rr < 4; ++rr) {
#pragma unroll
    for (int o = 1; o < 16; o <<= 1) sum[rr] += __shfl_xor(sum[rr], o, 64);
    sum[rr] = 1.0f / sum[rr];
  }
  __syncthreads();  // (2) all Ks reads done before Ps overlays

  // write P (own 9 tiles + 1 zero tile to cover the wave's 160-wide window)
#pragma unroll
  for (int j9 = 0; j9 < 9; ++j9) {
    const int jt = w + j9;
#pragma unroll
    for (int rr = 0; rr < 4; ++rr)
      Ps[(w * 16 + lq * 4 + rr) * 200 + jt * 16 + lr] = f2bf(sa[j9][rr] * sum[rr]);
  }
  {
    const int jz = (w == 0) ? 9 : (w == 1) ? 0 : (w == 2) ? 11 : 2;
#pragma unroll
    for (int rr = 0; rr < 4; ++rr) Ps[(w * 16 + lq * 4 + rr) * 200 + jz * 16 + lr] = 0;
  }
  // no barrier: pf reads only this wave's own Ps rows (footprint audit:
  // written tiles + zero tile exactly cover the wave's read window)
  asm volatile("" ::: "memory");

  // O = P*V over the wave's 160-wide window (5 K-steps, swizzled Vt reads)
  const int W = (w >> 1) * 32;  // halfword offset of the window
  const int G0 = W >> 3;
  f32x4 oa[4];
#pragma unroll
  for (int jt = 0; jt < 4; ++jt) oa[jt] = (f32x4){0.f, 0.f, 0.f, 0.f};
#pragma unroll
  for (int ks = 0; ks < 5; ++ks) {
    const bf16x8 pf = *(const bf16x8*)&Ps[(w * 16 + lr) * 200 + W + ks * 32 + lq * 8];
#pragma unroll
    for (int jt = 0; jt < 4; ++jt) {
      const int rl = jt * 16 + lr;
      const int g = G0 + ks * 4 + lq;
      const bf16x8 vf = *(const bf16x8*)&Vt[rl * 200 + ((g ^ (rl >> 3)) << 3)];
      oa[jt] = __builtin_amdgcn_mfma_f32_16x16x32_bf16(pf, vf, oa[jt], 0, 0, 0);
    }
  }
#pragma unroll
  for (int jt = 0; jt < 4; ++jt)
#pragma unroll
    for (int rr = 0; rr < 4; ++rr)
      loc[(size_t)(b * 1024 + i0 + w * 16 + lq * 4 + rr) * 1024 + h * 64 + jt * 16 + lr] =
          f2bf(oa[jt][rr]);

  // ===== compressed-KV phase (reuses qf; Kc/Vc/Pc overlay Ks/Ps region) =====
  __syncthreads();  // (3) all Ps reads done before overlay
#pragma unroll
  for (int c2 = 0; c2 < 2; ++c2) {
    const int i2 = c2 * 256 + tid;
    const int r2 = i2 >> 3, o2 = (i2 & 7) * 8;
    *(u32x4*)&Kc[r2 * 72 + o2] = kcreg[c2];
    *(u32x4*)&Vc[r2 * 72 + o2] = vcreg[c2];
  }
  __syncthreads();  // (4) Kc/Vc visible

  f32x4 ca[4];
#pragma unroll
  for (int j = 0; j < 4; ++j) ca[j] = (f32x4){0.f, 0.f, 0.f, 0.f};
#pragma unroll
  for (int ks = 0; ks < 2; ++ks)
#pragma unroll
    for (int j = 0; j < 4; ++j) {
      const bf16x8 kf = *(const bf16x8*)&Kc[(j * 16 + lr) * 72 + ks * 32 + lq * 8];
      ca[j] = __builtin_amdgcn_mfma_f32_16x16x32_bf16(qf[ks], kf, ca[j], 0, 0, 0);
    }
  float mc[4] = {NINF, NINF, NINF, NINF};
#pragma unroll
  for (int j = 0; j < 4; ++j) {
    const int s = j * 16 + lr;
#pragma unroll
    for (int rr = 0; rr < 4; ++rr) {
      const int i = i0 + w * 16 + lq * 4 + rr;
      const bool valid = (s <= i) && (s < 63);
      const float v = valid ? ca[j][rr] * 0.125f : NINF;
      ca[j][rr] = v;
      mc[rr] = fmaxf(mc[rr], v);
    }
  }
#pragma unroll
  for (int rr = 0; rr < 4; ++rr)
#pragma unroll
    for (int o = 1; o < 16; o <<= 1) mc[rr] = fmaxf(mc[rr], __shfl_xor(mc[rr], o, 64));
  float sc[4] = {0.f, 0.f, 0.f, 0.f};
#pragma unroll
  for (int j = 0; j < 4; ++j)
#pragma unroll
    for (int rr = 0; rr < 4; ++rr) {
      const float p = __expf(ca[j][rr] - mc[rr]);
      ca[j][rr] = p;
      sc[rr] += p;
    }
#pragma unroll
  for (int rr = 0; rr < 4; ++rr) {
#pragma unroll
    for (int o = 1; o < 16; o <<= 1) sc[rr] += __shfl_xor(sc[rr], o, 64);
    sc[rr] = 1.0f / sc[rr];
  }
#pragma unroll
  for (int j = 0; j < 4; ++j)
#pragma unroll
    for (int rr = 0; rr < 4; ++rr)
      Pc[(w * 16 + lq * 4 + rr) * 72 + j * 16 + lr] = f2bf(ca[j][rr] * sc[rr]);
  // no barrier: pf reads only this wave's own Pc rows; Pc region disjoint
  // from Kc/Vc so no cross-wave WAR either.
  asm volatile("" ::: "memory");

  f32x4 co[4];
#pragma unroll
  for (int jt = 0; jt < 4; ++jt) co[jt] = (f32x4){0.f, 0.f, 0.f, 0.f};
#pragma unroll
  for (int ks = 0; ks < 2; ++ks) {
    const bf16x8 pf = *(const bf16x8*)&Pc[(w * 16 + lr) * 72 + ks * 32 + lq * 8];
#pragma unroll
    for (int jt = 0; jt < 4; ++jt) {
      const bf16x8 vf = *(const bf16x8*)&Vc[(jt * 16 + lr) * 72 + ks * 32 + lq * 8];
      co[jt] = __builtin_amdgcn_mfma_f32_16x16x32_bf16(pf, vf, co[jt], 0, 0, 0);
    }
  }
#pragma unroll
  for (int jt = 0; jt < 4; ++jt)
#pragma unroll
    for (int rr = 0; rr < 4; ++rr)
      outc[(size_t)(b * 1024 + i0 + w * 16 + lq * 4 + rr) * 1024 + h * 64 + jt * 16 + lr] =
          f2bf(co[jt][rr]);
}

// ---------- gating GEMV (LN of local last rows folded in, round-4) ----------
__global__ __launch_bounds__(256) void gate_gemv(const u16* __restrict__ locb,
                                                 const u16* __restrict__ compb,
                                                 const float* __restrict__ lnw,
                                                 const float* __restrict__ w1,
                                                 float* __restrict__ hraw) {
  __shared__ float sm[8], sinv[8];
  const int tid = threadIdx.x;
  const int w = tid >> 6, lane = tid & 63;
  for (int bb = w; bb < 8; bb += 4) {
    const u16* rp = &locb[((size_t)bb * 1024 + 1023) * 1024 + lane * 16];
    const u32x4 a0 = *(const u32x4*)rp;
    const u32x4 a1 = *(const u32x4*)(rp + 8);
    float s = 0.f, s2 = 0.f;
#pragma unroll
    for (int q = 0; q < 4; ++q) {
      const float x0 = bflo(a0[q]), x1 = bfhi(a0[q]);
      const float x2 = bflo(a1[q]), x3 = bfhi(a1[q]);
      s += x0 + x1 + x2 + x3;
      s2 += x0 * x0 + x1 * x1 + x2 * x2 + x3 * x3;
    }
    s = wredsum(s);
    s2 = wredsum(s2);
    if (!lane) {
      const float m = s * (1.f / 1024.f);
      sm[bb] = m;
      sinv[bb] = rsqrtf(s2 * (1.f / 1024.f) - m * m + 1e-5f);
    }
  }
  __syncthreads();

  const int o = blockIdx.x * 4 + w;
  const float* wr = &w1[(size_t)o * 2048];
  float acc[8] = {};
#pragma unroll
  for (int it = 0; it < 4; ++it) {     // c in [0,1024): LN(local) on the fly
    const int c = (it * 64 + lane) * 4;
    const f32x4 wv = *(const f32x4*)&wr[c];
    const f32x4 lw = *(const f32x4*)&lnw[c];
#pragma unroll
    for (int b = 0; b < 8; ++b) {
      const f32x4 xv = unpack_bf4(*(const u32x2*)&locb[((size_t)b * 1024 + 1023) * 1024 + c]);
      const float mb = sm[b], ib = sinv[b];
      acc[b] += ((xv[0] - mb) * ib * lw[0]) * wv[0] + ((xv[1] - mb) * ib * lw[1]) * wv[1] +
                ((xv[2] - mb) * ib * lw[2]) * wv[2] + ((xv[3] - mb) * ib * lw[3]) * wv[3];
    }
  }
#pragma unroll
  for (int it = 4; it < 8; ++it) {     // c in [1024,2048): comp raw
    const int c = (it * 64 + lane) * 4;
    const f32x4 wv = *(const f32x4*)&wr[c];
    const int c2 = c - 1024;
#pragma unroll
    for (int b = 0; b < 8; ++b) {
      const f32x4 fv = unpack_bf4(*(const u32x2*)&compb[((size_t)b * 1024 + 1023) * 1024 + c2]);
      acc[b] += fv[0] * wv[0] + fv[1] * wv[1] + fv[2] * wv[2] + fv[3] * wv[3];
    }
  }
#pragma unroll
  for (int b = 0; b < 8; ++b) acc[b] = wredsum(acc[b]);
  if (lane == 0) {
#pragma unroll
    for (int b = 0; b < 8; ++b) hraw[b * 1024 + o] = acc[b];
  }
}

// ---------- combine (round-8: gate_fin folded in) ----------
// Each block recomputes the gates for its batch b redundantly from hraw
// (4KB L2-hot; bitwise-identical op order to the old gate_fin kernel),
// then does the per-row LN + gate-combine + bf16 cast (wave-per-row).
__global__ __launch_bounds__(256) void combine_ln_cast(const u16* __restrict__ locb,
                                                       const u16* __restrict__ compb,
                                                       const float* __restrict__ lnw,
                                                       const float* __restrict__ glnw,
                                                       const float* __restrict__ w2,
                                                       const float* __restrict__ hraw,
                                                       u16* __restrict__ outb) {
  const int tid = threadIdx.x;
  const int w = tid >> 6, lane = tid & 63;
  const int b = (blockIdx.x * 4) >> 10;   // 4 rows/block never straddle a batch

  // ---- gates for batch b (all threads; identical to old gate_fin) ----
  __shared__ float rs[4], rs2[4];
  const f32x4 hv = *(const f32x4*)&hraw[(size_t)b * 1024 + tid * 4];
  {
    float s = hv[0] + hv[1] + hv[2] + hv[3];
    float s2 = hv[0] * hv[0] + hv[1] * hv[1] + hv[2] * hv[2] + hv[3] * hv[3];
    s = wredsum(s);
    s2 = wredsum(s2);
    if (!lane) { rs[w] = s; rs2[w] = s2; }
  }
  __syncthreads();
  float g0, g1;
  {
    const float s = rs[0] + rs[1] + rs[2] + rs[3];
    const float s2 = rs2[0] + rs2[1] + rs2[2] + rs2[3];
    const float m = s * (1.f / 1024.f);
    const float inv = rsqrtf(s2 * (1.f / 1024.f) - m * m + 1e-5f);
    float p0 = 0.f, p1 = 0.f;
#pragma unroll
    for (int k = 0; k < 4; ++k) {
      float hh = (hv[k] - m) * inv * glnw[tid * 4 + k];
      hh = fmaxf(hh, 0.f);
      p0 += hh * w2[tid * 4 + k];
      p1 += hh * w2[1024 + tid * 4 + k];
    }
    p0 = wredsum(p0);
    p1 = wredsum(p1);
    __syncthreads();                      // rs reuse (WAR)
    if (!lane) { rs[w] = p0; rs2[w] = p1; }
    __syncthreads();
    const float l0 = rs[0] + rs[1] + rs[2] + rs[3];
    const float l1 = rs2[0] + rs2[1] + rs2[2] + rs2[3];
    const float mm = fmaxf(l0, l1);
    const float e0 = __expf(l0 - mm), e1 = __expf(l1 - mm);
    const float iv = 1.f / (e0 + e1);
    g0 = e0 * iv;
    g1 = e1 * iv;
  }

  // ---- per-row LN + combine (wave-per-row, no further barriers) ----
  const int row = blockIdx.x * 4 + w;
  const size_t base = (size_t)row * 1024 + lane * 16;
  const u32x4 a0 = *(const u32x4*)&locb[base];
  const u32x4 a1 = *(const u32x4*)&locb[base + 8];
  float xv[16];
#pragma unroll
  for (int q = 0; q < 4; ++q) {
    xv[2 * q] = bflo(a0[q]);
    xv[2 * q + 1] = bfhi(a0[q]);
    xv[8 + 2 * q] = bflo(a1[q]);
    xv[8 + 2 * q + 1] = bfhi(a1[q]);
  }
  float s = 0.f, s2 = 0.f;
#pragma unroll
  for (int k = 0; k < 16; ++k) {
    s += xv[k];
    s2 += xv[k] * xv[k];
  }
  s = wredsum(s);
  s2 = wredsum(s2);
  const float m = s * (1.f / 1024.f);
  const float inv = rsqrtf(s2 * (1.f / 1024.f) - m * m + 1e-5f);
  const u32x4 c0 = *(const u32x4*)&compb[base];
  const u32x4 c1 = *(const u32x4*)&compb[base + 8];
  const f32x4 lw0 = *(const f32x4*)&lnw[lane * 16];
  const f32x4 lw1 = *(const f32x4*)&lnw[lane * 16 + 4];
  const f32x4 lw2 = *(const f32x4*)&lnw[lane * 16 + 8];
  const f32x4 lw3 = *(const f32x4*)&lnw[lane * 16 + 12];
  u32x4 r0, r1;
#pragma unroll
  for (int q = 0; q < 4; ++q) {
    const float lwa = (q < 2) ? lw0[2 * q] : lw1[2 * q - 4];
    const float lwb = (q < 2) ? lw0[2 * q + 1] : lw1[2 * q - 3];
    const float lwc = (q < 2) ? lw2[2 * q] : lw3[2 * q - 4];
    const float lwd = (q < 2) ? lw2[2 * q + 1] : lw3[2 * q - 3];
    const float o0 = g0 * ((xv[2 * q] - m) * inv * lwa) + g1 * bflo(c0[q]);
    const float o1 = g0 * ((xv[2 * q + 1] - m) * inv * lwb) + g1 * bfhi(c0[q]);
    const float o2 = g0 * ((xv[8 + 2 * q] - m) * inv * lwc) + g1 * bflo(c1[q]);
    const float o3 = g0 * ((xv[8 + 2 * q + 1] - m) * inv * lwd) + g1 * bfhi(c1[q]);
    r0[q] = (u32)f2bf(o0) | ((u32)f2bf(o1) << 16);
    r1[q] = (u32)f2bf(o2) | ((u32)f2bf(o3) << 16);
  }
  *(u32x4*)&outb[base] = r0;
  *(u32x4*)&outb[base + 8] = r1;
}

// ---------- launcher ----------
extern "C" void kernel_launch(void* const* d_in, const int* in_sizes, int n_in,
                              void* d_out, int out_size, void* d_ws, size_t ws_size,
                              hipStream_t stream) {
  const float* x = (const float*)d_in[0];
  const float* c_attn_w = (const float*)d_in[1];
  const float* conv_w = (const float*)d_in[2];
  const float* ln_comp_w = (const float*)d_in[3];
  const float* ln_local_w = (const float*)d_in[4];
  const float* gate_w1 = (const float*)d_in[5];
  const float* gate_ln_w = (const float*)d_in[6];
  const float* gate_w2 = (const float*)d_in[7];
  const float* c_proj_w = (const float*)d_in[8];
  float* y = (float*)d_out;

  char* ws = (char*)d_ws;
  size_t off = 0;
  auto alloc = [&](size_t bytes) -> void* {
    void* p = ws + off;
    off += (bytes + 255) & ~(size_t)255;
    return p;
  };
  u16* qkvb = (u16*)alloc((size_t)8192 * 3072 * 2);
  u16* xb = (u16*)alloc((size_t)8192 * 1024 * 2);
  u16* wab = (u16*)alloc((size_t)3072 * 1024 * 2);
  u16* wpb = (u16*)alloc((size_t)1024 * 1024 * 2);
  u16* wcb = (u16*)alloc((size_t)64 * 2048 * 2);
  u16* kcb = (u16*)alloc((size_t)128 * 4096 * 2);  // [bh][nb(64)][d] bf16
  u16* vcb = (u16*)alloc((size_t)128 * 4096 * 2);  // [bh][d][nb(64)] bf16
  u16* locb = (u16*)alloc((size_t)8192 * 1024 * 2);
  u16* compb = (u16*)alloc((size_t)8192 * 1024 * 2);
  float* hraw = (float*)alloc((size_t)8192 * 4);
  u16* combb = (u16*)alloc((size_t)8192 * 1024 * 2);

  fused_cast<<<12801, 256, 0, stream>>>(x, c_attn_w, c_proj_w, conv_w, xb, wab, wpb, wcb, kcb,
                                        vcb);

  gemm_bt<1><<<dim3(64, 24), 256, 0, stream>>>(xb, wab, qkvb, 8192, 3072, 1024);

  compress_kernel<<<dim3(252, 2), 256, 0, stream>>>(qkvb, wcb, ln_comp_w, kcb, vcb);

  attn_fused<<<dim3(128, 16), 256, 0, stream>>>(qkvb, kcb, vcb, locb, compb);

  gate_gemv<<<256, 256, 0, stream>>>(locb, compb, ln_local_w, gate_w1, hraw);

  combine_ln_cast<<<2048, 256, 0, stream>>>(locb, compb, ln_local_w, gate_ln_w, gate_w2, hraw,
                                            combb);

  gemm_bt<0><<<dim3(64, 8), 256, 0, stream>>>(combb, wpb, y, 8192, 1024, 1024);
}